// Round 6
// baseline (808.334 us; speedup 1.0000x reference)
//
#include <hip/hip_runtime.h>

#define IN_CH 128
#define HID   64
#define NC    10
#define BSH   7       // 128 nodes per bucket
#define NBLK  256     // partition blocks

typedef unsigned short bfu;

static __device__ __forceinline__ bfu bf16_of(float f) {
    unsigned u = __float_as_uint(f);
    unsigned r = (u + 0x7FFF + ((u >> 16) & 1)) >> 16;   // RNE
    return (bfu)r;
}
static __device__ __forceinline__ float f_of_bf16(bfu u) {
    return __uint_as_float(((unsigned)u) << 16);
}

__device__ __forceinline__ int lower_bound_i(const int* a, int n, int v) {
    int lo = 0, hi = n;
    while (lo < hi) { int mid = (lo + hi) >> 1; if (a[mid] < v) lo = mid + 1; else hi = mid; }
    return lo;
}

// ---- fused degree count + per-(block,bucket) histogram ------------------

__global__ void k_count_hist(const int* __restrict__ dst, int* __restrict__ cnt,
                             int* __restrict__ Gh, int E, int nbuck, int chunk) {
    extern __shared__ int h[];
    for (int b = threadIdx.x; b < nbuck; b += blockDim.x) h[b] = 0;
    __syncthreads();
    int base = blockIdx.x * chunk;
    int lim  = min(base + chunk, E);
    for (int e = base + threadIdx.x; e < lim; e += blockDim.x) {
        int d = dst[e];
        atomicAdd(&cnt[d], 1);
        atomicAdd(&h[d >> BSH], 1);
    }
    __syncthreads();
    for (int b = threadIdx.x; b < nbuck; b += blockDim.x)
        Gh[b * NBLK + blockIdx.x] = h[b];
}

// ---- rowptr scan --------------------------------------------------------

__global__ void k_scan1(const int* __restrict__ cnt, int* __restrict__ excl,
                        int* __restrict__ bsum, int n) {
    __shared__ int s[256];
    int i = blockIdx.x * 256 + threadIdx.x;
    int v = (i < n) ? cnt[i] : 0;
    s[threadIdx.x] = v;
    __syncthreads();
    for (int off = 1; off < 256; off <<= 1) {
        int t = (threadIdx.x >= off) ? s[threadIdx.x - off] : 0;
        __syncthreads();
        s[threadIdx.x] += t;
        __syncthreads();
    }
    if (i < n) excl[i] = s[threadIdx.x] - v;
    if (threadIdx.x == 255) bsum[blockIdx.x] = s[255];
}

__global__ void k_scan2(int* __restrict__ bsum, int nb) {
    __shared__ int s[512];
    int v = (threadIdx.x < nb) ? bsum[threadIdx.x] : 0;
    s[threadIdx.x] = v;
    __syncthreads();
    for (int off = 1; off < 512; off <<= 1) {
        int t = (threadIdx.x >= off) ? s[threadIdx.x - off] : 0;
        __syncthreads();
        s[threadIdx.x] += t;
        __syncthreads();
    }
    if (threadIdx.x < nb) bsum[threadIdx.x] = s[threadIdx.x] - v;
}

__global__ void k_scan3(int* __restrict__ rowptr, const int* __restrict__ bsum,
                        int n, int E) {
    int i = blockIdx.x * 256 + threadIdx.x;
    if (i < n) rowptr[i] = rowptr[i] + bsum[i >> 8];
    if (i == 0) rowptr[n] = E;
}

__global__ void k_dinv(const int* __restrict__ cnt, float* __restrict__ dinv, int n) {
    int i = blockIdx.x * blockDim.x + threadIdx.x;
    if (i < n) dinv[i] = rsqrtf((float)(cnt[i] + 1));  // +1 self loop
}

// ---- scan of Gh (bucket-major) + bucket starts --------------------------

__global__ void k_scanG(int* __restrict__ Gh, int* __restrict__ bstart,
                        int n, int nbuck, int E) {
    __shared__ int tot[1024];
    const int T = 1024;
    int L = (n + T - 1) / T;
    int lo = threadIdx.x * L, hi = min(lo + L, n);
    int s = 0;
    for (int i = lo; i < hi; i++) s += Gh[i];
    tot[threadIdx.x] = s;
    __syncthreads();
    for (int off = 1; off < T; off <<= 1) {
        int t = (threadIdx.x >= off) ? tot[threadIdx.x - off] : 0;
        __syncthreads();
        tot[threadIdx.x] += t;
        __syncthreads();
    }
    int run = tot[threadIdx.x] - s;
    for (int i = lo; i < hi; i++) {
        int v = Gh[i];
        Gh[i] = run;
        if ((i & (NBLK - 1)) == 0) bstart[i / NBLK] = run;
        run += v;
    }
    if (threadIdx.x == 0) bstart[nbuck] = E;
}

// ---- partB: scatter (src,dst) into bucket-grouped order -----------------

__global__ void k_partB(const int* __restrict__ src, const int* __restrict__ dst,
                        const int* __restrict__ Gh, int2* __restrict__ packed,
                        int E, int nbuck, int chunk) {
    extern __shared__ int cur[];
    for (int b = threadIdx.x; b < nbuck; b += blockDim.x)
        cur[b] = Gh[b * NBLK + blockIdx.x];
    __syncthreads();
    int base = blockIdx.x * chunk;
    int lim  = min(base + chunk, E);
    for (int e = base + threadIdx.x; e < lim; e += blockDim.x) {
        int d = dst[e], s = src[e];
        int pos = atomicAdd(&cur[d >> BSH], 1);
        packed[pos] = make_int2(s, d);
    }
}

// ---- placeC: one block per bucket; dense ~8KB meta span -----------------

__global__ void k_placeC(const int2* __restrict__ packed, const int* __restrict__ bstart,
                         const int* __restrict__ rowptr, int* __restrict__ meta, int nn) {
    __shared__ int cur[1 << BSH];
    int b   = blockIdx.x;
    int nb0 = b << BSH;
    int nnb = min(1 << BSH, nn - nb0);
    for (int j = threadIdx.x; j < nnb; j += blockDim.x) cur[j] = rowptr[nb0 + j];
    __syncthreads();
    int lo = bstart[b], hi = bstart[b + 1];
    for (int e = lo + threadIdx.x; e < hi; e += blockDim.x) {
        int2 p = packed[e];
        int pos = atomicAdd(&cur[p.y - nb0], 1);
        meta[pos] = p.x;
    }
}

// ---- Dense X@W + dinv-scaled bf16 epilogue ------------------------------

template <int K, bool IN_BF16>
__global__ __launch_bounds__(256) void k_gemm(const void* __restrict__ Xv,
                                              const float* __restrict__ W,
                                              const float* __restrict__ dinv,
                                              bfu* __restrict__ G, int n) {
    __shared__ float4 xs4[128][8];
    __shared__ float4 ws4[32][16];
    int tid  = threadIdx.x;
    int row0 = blockIdx.x * 128;
    int cg = tid & 15, rg = tid >> 4;
    float acc[8][4];
#pragma unroll
    for (int r = 0; r < 8; r++)
#pragma unroll
        for (int c = 0; c < 4; c++) acc[r][c] = 0.f;

    for (int k0 = 0; k0 < K; k0 += 32) {
        int sr = tid >> 3, f4 = tid & 7;
#pragma unroll
        for (int i = 0; i < 4; i++) {
            int row  = sr + i * 32;
            int grow = row0 + row;
            float4 v = make_float4(0.f, 0.f, 0.f, 0.f);
            if (grow < n) {
                if (IN_BF16) {
                    const bfu* X = (const bfu*)Xv;
                    ushort4 u = *(const ushort4*)&X[(size_t)grow * K + k0 + f4 * 4];
                    v = make_float4(f_of_bf16(u.x), f_of_bf16(u.y),
                                    f_of_bf16(u.z), f_of_bf16(u.w));
                } else {
                    const float* X = (const float*)Xv;
                    v = *(const float4*)&X[(size_t)grow * K + k0 + f4 * 4];
                }
            }
            xs4[row][f4 ^ ((row >> 3) & 3)] = v;
        }
        {
            const float4* Wp = (const float4*)&W[(size_t)k0 * 64];
            int j0 = tid, j1 = tid + 256;
            ws4[j0 >> 4][j0 & 15] = Wp[j0];
            ws4[j1 >> 4][j1 & 15] = Wp[j1];
        }
        __syncthreads();
#pragma unroll
        for (int k4 = 0; k4 < 8; k4++) {
            float4 av[8];
#pragma unroll
            for (int r = 0; r < 8; r++) av[r] = xs4[rg * 8 + r][k4 ^ (rg & 3)];
            float4 wv[4];
#pragma unroll
            for (int kk = 0; kk < 4; kk++) wv[kk] = ws4[k4 * 4 + kk][cg];
#pragma unroll
            for (int kk = 0; kk < 4; kk++) {
#pragma unroll
                for (int r = 0; r < 8; r++) {
                    float a = ((const float*)&av[r])[kk];
                    acc[r][0] += a * wv[kk].x;
                    acc[r][1] += a * wv[kk].y;
                    acc[r][2] += a * wv[kk].z;
                    acc[r][3] += a * wv[kk].w;
                }
            }
        }
        __syncthreads();
    }
#pragma unroll
    for (int r = 0; r < 8; r++) {
        int row = row0 + rg * 8 + r;
        if (row < n) {
            float dv = dinv[row];
            ushort4 o;
            o.x = bf16_of(acc[r][0] * dv);
            o.y = bf16_of(acc[r][1] * dv);
            o.z = bf16_of(acc[r][2] * dv);
            o.w = bf16_of(acc[r][3] * dv);
            *(ushort4*)&G[(size_t)row * 64 + cg * 4] = o;
        }
    }
}

// ---- CSR gather agg: wave/node, lane=col, branchless 16-deep MLP --------

__global__ void k_agg(const bfu* __restrict__ G, const int* __restrict__ meta,
                      const int* __restrict__ rowptr, const float* __restrict__ dinv,
                      const float* __restrict__ bias, bfu* __restrict__ out,
                      int n, int do_relu, int post_scale) {
    int wid  = (blockIdx.x * blockDim.x + threadIdx.x) >> 6;
    int lane = threadIdx.x & 63;
    if (wid >= n) return;
    int beg = rowptr[wid], end = rowptr[wid + 1];
    float a[8];
    a[0] = f_of_bf16(G[(size_t)wid * 64 + lane]);  // self loop (pre-scaled)
#pragma unroll
    for (int j = 1; j < 8; j++) a[j] = 0.f;
    for (int e = beg; e < end; e += 16) {
        int m[16];
#pragma unroll
        for (int j = 0; j < 16; j++) {
            int ej = e + j;
            m[j] = meta[(ej < end) ? ej : beg];   // branchless clamp
        }
#pragma unroll
        for (int j = 0; j < 16; j++) {
            float v = f_of_bf16(G[(size_t)m[j] * 64 + lane]);
            a[j & 7] += (e + j < end) ? v : 0.f;
        }
    }
    float acc = ((a[0] + a[1]) + (a[2] + a[3])) + ((a[4] + a[5]) + (a[6] + a[7]));
    float dv = dinv[wid];
    acc *= dv;
    if (bias) acc += bias[lane];
    if (do_relu) acc = fmaxf(acc, 0.f);
    if (post_scale) acc *= dv;
    out[(size_t)wid * 64 + lane] = bf16_of(acc);
}

// ---- Mean pool, chunk-parallel (bf16 input, fp32 accum) -----------------

__global__ void k_pool(const bfu* __restrict__ G, const int* __restrict__ batch,
                       float* __restrict__ Psum, int n) {
    int base = blockIdx.x * 256;
    int lane = threadIdx.x & 63, rg = threadIdx.x >> 6;
    int lim = min(base + 256, n);
    int cur = -1;
    float acc = 0.f;
    for (int r = base + rg; r < lim; r += 4) {
        int g = batch[r];
        if (g != cur) {
            if (cur >= 0) atomicAdd(&Psum[cur * 64 + lane], acc);
            cur = g;
            acc = 0.f;
        }
        acc += f_of_bf16(G[(size_t)r * 64 + lane]);
    }
    if (cur >= 0) atomicAdd(&Psum[cur * 64 + lane], acc);
}

// ---- mean + pooled@W3 + b3 + log_softmax --------------------------------

__global__ void k_final(const float* __restrict__ Psum, const int* __restrict__ batch,
                        int n, const float* __restrict__ W3, const float* __restrict__ b3,
                        float* __restrict__ out, int ng) {
    __shared__ float P[64 * 64];
    __shared__ float s[64][NC];
    __shared__ float lse[64];
    __shared__ float invc[64];
    int t = threadIdx.x;
    if (t < ng) {
        int lo = lower_bound_i(batch, n, t);
        int hi = lower_bound_i(batch, n, t + 1);
        invc[t] = 1.f / (float)max(hi - lo, 1);
    }
    __syncthreads();
    for (int i = t; i < ng * 64; i += blockDim.x) P[i] = Psum[i] * invc[i >> 6];
    __syncthreads();
    if (t < ng * NC) {
        int g = t / NC, c = t % NC;
        float acc = b3[c];
        for (int k = 0; k < 64; k++) acc += P[g * 64 + k] * W3[k * NC + c];
        s[g][c] = acc;
    }
    __syncthreads();
    if (t < ng) {
        float m = -1e30f;
        for (int c = 0; c < NC; c++) m = fmaxf(m, s[t][c]);
        float sum = 0.f;
        for (int c = 0; c < NC; c++) sum += expf(s[t][c] - m);
        lse[t] = m + logf(sum);
    }
    __syncthreads();
    if (t < ng * NC) {
        int g = t / NC, c = t % NC;
        out[t] = s[g][c] - lse[g];
    }
}

// ---- launch -------------------------------------------------------------

extern "C" void kernel_launch(void* const* d_in, const int* in_sizes, int n_in,
                              void* d_out, int out_size, void* d_ws, size_t ws_size,
                              hipStream_t stream) {
    const float* x     = (const float*)d_in[0];
    const int*   ei    = (const int*)  d_in[1];
    const int*   batch = (const int*)  d_in[2];
    const float* W1    = (const float*)d_in[3];
    const float* b1    = (const float*)d_in[4];
    const float* W2    = (const float*)d_in[5];
    const float* b2    = (const float*)d_in[6];
    const float* W3    = (const float*)d_in[7];
    const float* b3    = (const float*)d_in[8];
    float*       out   = (float*)d_out;

    const int NN = in_sizes[0] / IN_CH;   // 100000
    const int E  = in_sizes[1] / 2;       // 1600000
    const int NG = out_size / NC;         // 64
    const int nbuck = (NN + (1 << BSH) - 1) >> BSH;  // 782

    const int* src = ei;
    const int* dst = ei + E;

    char* ws = (char*)d_ws;
    size_t off = 0;
    auto carve = [&](size_t bytes) -> char* {
        char* p = ws + off;
        off = (off + bytes + 255) & ~(size_t)255;
        return p;
    };
    int*   cnt    = (int*)  carve((size_t)NN * 4);
    int*   rowptr = (int*)  carve((size_t)(NN + 1) * 4);
    float* dinv   = (float*)carve((size_t)NN * 4);
    int*   bsum   = (int*)  carve(4096);
    int*   bstart = (int*)  carve((size_t)(nbuck + 1) * 4);
    int*   Gh     = (int*)  carve((size_t)nbuck * NBLK * 4);
    int*   meta   = (int*)  carve((size_t)E * 4);
    bfu*   bufA   = (bfu*)  carve((size_t)NN * HID * 2);
    bfu*   bufB   = (bfu*)  carve((size_t)NN * HID * 2);
    float* Psum   = (float*)carve((size_t)NG * HID * 4);
    (void)ws_size;

    // packed aliases bufA+bufB region? bufA alone: E*8 = 12.8MB == bufA size.
    int2* packed = (int2*)bufA;

    const int nbN  = (NN + 255) / 256;
    const int chnk = (E + NBLK - 1) / NBLK;
    const size_t lds_h = (size_t)nbuck * 4;

    hipMemsetAsync(cnt, 0, (size_t)NN * 4, stream);
    hipMemsetAsync(Psum, 0, (size_t)NG * HID * 4, stream);
    k_count_hist<<<NBLK, 256, lds_h, stream>>>(dst, cnt, Gh, E, nbuck, chnk);
    k_scan1<<<nbN, 256, 0, stream>>>(cnt, rowptr, bsum, NN);
    k_scan2<<<1, 512, 0, stream>>>(bsum, nbN);
    k_scan3<<<nbN, 256, 0, stream>>>(rowptr, bsum, NN, E);
    k_dinv <<<nbN, 256, 0, stream>>>(cnt, dinv, NN);
    k_scanG <<<1, 1024, 0, stream>>>(Gh, bstart, nbuck * NBLK, nbuck, E);
    k_partB <<<NBLK, 256, lds_h, stream>>>(src, dst, Gh, packed, E, nbuck, chnk);
    k_placeC<<<nbuck, 256, 0, stream>>>(packed, bstart, rowptr, meta, NN);

    const int nbG = (NN + 127) / 128;
    const int nbA = ((size_t)NN * 64 + 255) / 256;

    // layer 1: G1 = dinv*(x@W1) ; H1 = relu(dinv*(G1[v]+sum G1[src]) + b1)
    k_gemm<IN_CH, false><<<nbG, 256, 0, stream>>>(x, W1, dinv, bufA, NN);
    k_agg<<<nbA, 256, 0, stream>>>(bufA, meta, rowptr, dinv, b1, bufB, NN, 1, 0);
    // layer 2
    k_gemm<HID, true><<<nbG, 256, 0, stream>>>(bufB, W2, dinv, bufA, NN);
    k_agg<<<nbA, 256, 0, stream>>>(bufA, meta, rowptr, dinv, b2, bufB, NN, 1, 1);
    // layer 3 (reordered) + pool + head
    k_agg<<<nbA, 256, 0, stream>>>(bufB, meta, rowptr, dinv, nullptr, bufA, NN, 0, 0);
    k_pool<<<nbN, 256, 0, stream>>>(bufA, batch, Psum, NN);
    k_final<<<1, 640, 0, stream>>>(Psum, batch, NN, W3, b3, out, NG);
}

// Round 7
// 488.467 us; speedup vs baseline: 1.6548x; 1.6548x over previous
//
#include <hip/hip_runtime.h>

#define IN_CH 128
#define HID   64
#define NC    10
#define BSH   7       // 128 nodes per bucket
#define NBLK  256     // partition blocks

typedef unsigned short bfu;

static __device__ __forceinline__ bfu bf16_of(float f) {
    unsigned u = __float_as_uint(f);
    unsigned r = (u + 0x7FFF + ((u >> 16) & 1)) >> 16;   // RNE
    return (bfu)r;
}
static __device__ __forceinline__ float f_of_bf16(bfu u) {
    return __uint_as_float(((unsigned)u) << 16);
}

__device__ __forceinline__ int lower_bound_i(const int* a, int n, int v) {
    int lo = 0, hi = n;
    while (lo < hi) { int mid = (lo + hi) >> 1; if (a[mid] < v) lo = mid + 1; else hi = mid; }
    return lo;
}

// ---- fused degree count + per-(block,bucket) histogram ------------------

__global__ void k_count_hist(const int* __restrict__ dst, int* __restrict__ cnt,
                             int* __restrict__ Gh, int E, int nbuck, int chunk) {
    extern __shared__ int h[];
    for (int b = threadIdx.x; b < nbuck; b += blockDim.x) h[b] = 0;
    __syncthreads();
    int base = blockIdx.x * chunk;
    int lim  = min(base + chunk, E);
    for (int e = base + threadIdx.x; e < lim; e += blockDim.x) {
        int d = dst[e];
        atomicAdd(&cnt[d], 1);
        atomicAdd(&h[d >> BSH], 1);
    }
    __syncthreads();
    for (int b = threadIdx.x; b < nbuck; b += blockDim.x)
        Gh[b * NBLK + blockIdx.x] = h[b];
}

// ---- generic hierarchical exclusive scan pieces -------------------------

__global__ void k_scan1(const int* __restrict__ cnt, int* __restrict__ excl,
                        int* __restrict__ bsum, int n) {
    __shared__ int s[256];
    int i = blockIdx.x * 256 + threadIdx.x;
    int v = (i < n) ? cnt[i] : 0;
    s[threadIdx.x] = v;
    __syncthreads();
    for (int off = 1; off < 256; off <<= 1) {
        int t = (threadIdx.x >= off) ? s[threadIdx.x - off] : 0;
        __syncthreads();
        s[threadIdx.x] += t;
        __syncthreads();
    }
    if (i < n) excl[i] = s[threadIdx.x] - v;
    if (threadIdx.x == 255) bsum[blockIdx.x] = s[255];
}

// 1024-thread single-block exclusive scan (nb <= 1024), in place
__global__ void k_scan2(int* __restrict__ bsum, int nb) {
    __shared__ int s[1024];
    int v = (threadIdx.x < nb) ? bsum[threadIdx.x] : 0;
    s[threadIdx.x] = v;
    __syncthreads();
    for (int off = 1; off < 1024; off <<= 1) {
        int t = (threadIdx.x >= off) ? s[threadIdx.x - off] : 0;
        __syncthreads();
        s[threadIdx.x] += t;
        __syncthreads();
    }
    if (threadIdx.x < nb) bsum[threadIdx.x] = s[threadIdx.x] - v;
}

__global__ void k_scan3(int* __restrict__ rowptr, const int* __restrict__ bsum,
                        int n, int E) {
    int i = blockIdx.x * 256 + threadIdx.x;
    if (i < n) rowptr[i] = rowptr[i] + bsum[i >> 8];
    if (i == 0) rowptr[n] = E;
}

// add block offsets to Gh and extract bucket starts
__global__ void k_scan3g(int* __restrict__ Gh, const int* __restrict__ bsum,
                         int* __restrict__ bstart, int n, int nbuck, int E) {
    int i = blockIdx.x * 256 + threadIdx.x;
    if (i < n) {
        int v = Gh[i] + bsum[i >> 8];
        Gh[i] = v;
        if ((i & (NBLK - 1)) == 0) bstart[i / NBLK] = v;
    }
    if (i == 0) bstart[nbuck] = E;
}

__global__ void k_dinv(const int* __restrict__ cnt, float* __restrict__ dinv, int n) {
    int i = blockIdx.x * blockDim.x + threadIdx.x;
    if (i < n) dinv[i] = rsqrtf((float)(cnt[i] + 1));  // +1 self loop
}

// ---- partB: scatter (src,dst) into bucket-grouped order -----------------

__global__ void k_partB(const int* __restrict__ src, const int* __restrict__ dst,
                        const int* __restrict__ Gh, int2* __restrict__ packed,
                        int E, int nbuck, int chunk) {
    extern __shared__ int cur[];
    for (int b = threadIdx.x; b < nbuck; b += blockDim.x)
        cur[b] = Gh[b * NBLK + blockIdx.x];
    __syncthreads();
    int base = blockIdx.x * chunk;
    int lim  = min(base + chunk, E);
    for (int e = base + threadIdx.x; e < lim; e += blockDim.x) {
        int d = dst[e], s = src[e];
        int pos = atomicAdd(&cur[d >> BSH], 1);
        packed[pos] = make_int2(s, d);
    }
}

// ---- placeC: one block per bucket; dense ~8KB meta span -----------------

__global__ void k_placeC(const int2* __restrict__ packed, const int* __restrict__ bstart,
                         const int* __restrict__ rowptr, int* __restrict__ meta, int nn) {
    __shared__ int cur[1 << BSH];
    int b   = blockIdx.x;
    int nb0 = b << BSH;
    int nnb = min(1 << BSH, nn - nb0);
    for (int j = threadIdx.x; j < nnb; j += blockDim.x) cur[j] = rowptr[nb0 + j];
    __syncthreads();
    int lo = bstart[b], hi = bstart[b + 1];
    for (int e = lo + threadIdx.x; e < hi; e += blockDim.x) {
        int2 p = packed[e];
        int pos = atomicAdd(&cur[p.y - nb0], 1);
        meta[pos] = p.x;
    }
}

// ---- Dense X@W + dinv-scaled bf16 epilogue ------------------------------

template <int K, bool IN_BF16>
__global__ __launch_bounds__(256) void k_gemm(const void* __restrict__ Xv,
                                              const float* __restrict__ W,
                                              const float* __restrict__ dinv,
                                              bfu* __restrict__ G, int n) {
    __shared__ float4 xs4[128][8];
    __shared__ float4 ws4[32][16];
    int tid  = threadIdx.x;
    int row0 = blockIdx.x * 128;
    int cg = tid & 15, rg = tid >> 4;
    float acc[8][4];
#pragma unroll
    for (int r = 0; r < 8; r++)
#pragma unroll
        for (int c = 0; c < 4; c++) acc[r][c] = 0.f;

    for (int k0 = 0; k0 < K; k0 += 32) {
        int sr = tid >> 3, f4 = tid & 7;
#pragma unroll
        for (int i = 0; i < 4; i++) {
            int row  = sr + i * 32;
            int grow = row0 + row;
            float4 v = make_float4(0.f, 0.f, 0.f, 0.f);
            if (grow < n) {
                if (IN_BF16) {
                    const bfu* X = (const bfu*)Xv;
                    ushort4 u = *(const ushort4*)&X[(size_t)grow * K + k0 + f4 * 4];
                    v = make_float4(f_of_bf16(u.x), f_of_bf16(u.y),
                                    f_of_bf16(u.z), f_of_bf16(u.w));
                } else {
                    const float* X = (const float*)Xv;
                    v = *(const float4*)&X[(size_t)grow * K + k0 + f4 * 4];
                }
            }
            xs4[row][f4 ^ ((row >> 3) & 3)] = v;
        }
        {
            const float4* Wp = (const float4*)&W[(size_t)k0 * 64];
            int j0 = tid, j1 = tid + 256;
            ws4[j0 >> 4][j0 & 15] = Wp[j0];
            ws4[j1 >> 4][j1 & 15] = Wp[j1];
        }
        __syncthreads();
#pragma unroll
        for (int k4 = 0; k4 < 8; k4++) {
            float4 av[8];
#pragma unroll
            for (int r = 0; r < 8; r++) av[r] = xs4[rg * 8 + r][k4 ^ (rg & 3)];
            float4 wv[4];
#pragma unroll
            for (int kk = 0; kk < 4; kk++) wv[kk] = ws4[k4 * 4 + kk][cg];
#pragma unroll
            for (int kk = 0; kk < 4; kk++) {
#pragma unroll
                for (int r = 0; r < 8; r++) {
                    float a = ((const float*)&av[r])[kk];
                    acc[r][0] += a * wv[kk].x;
                    acc[r][1] += a * wv[kk].y;
                    acc[r][2] += a * wv[kk].z;
                    acc[r][3] += a * wv[kk].w;
                }
            }
        }
        __syncthreads();
    }
#pragma unroll
    for (int r = 0; r < 8; r++) {
        int row = row0 + rg * 8 + r;
        if (row < n) {
            float dv = dinv[row];
            ushort4 o;
            o.x = bf16_of(acc[r][0] * dv);
            o.y = bf16_of(acc[r][1] * dv);
            o.z = bf16_of(acc[r][2] * dv);
            o.w = bf16_of(acc[r][3] * dv);
            *(ushort4*)&G[(size_t)row * 64 + cg * 4] = o;
        }
    }
}

// ---- CSR gather agg: wave/node, lane=col, branchless 16-deep MLP --------

__global__ void k_agg(const bfu* __restrict__ G, const int* __restrict__ meta,
                      const int* __restrict__ rowptr, const float* __restrict__ dinv,
                      const float* __restrict__ bias, bfu* __restrict__ out,
                      int n, int do_relu, int post_scale) {
    int wid  = (blockIdx.x * blockDim.x + threadIdx.x) >> 6;
    int lane = threadIdx.x & 63;
    if (wid >= n) return;
    int beg = rowptr[wid], end = rowptr[wid + 1];
    float a[8];
    a[0] = f_of_bf16(G[(size_t)wid * 64 + lane]);  // self loop (pre-scaled)
#pragma unroll
    for (int j = 1; j < 8; j++) a[j] = 0.f;
    for (int e = beg; e < end; e += 16) {
        int m[16];
#pragma unroll
        for (int j = 0; j < 16; j++) {
            int ej = e + j;
            m[j] = meta[(ej < end) ? ej : beg];   // branchless clamp
        }
#pragma unroll
        for (int j = 0; j < 16; j++) {
            float v = f_of_bf16(G[(size_t)m[j] * 64 + lane]);
            a[j & 7] += (e + j < end) ? v : 0.f;
        }
    }
    float acc = ((a[0] + a[1]) + (a[2] + a[3])) + ((a[4] + a[5]) + (a[6] + a[7]));
    float dv = dinv[wid];
    acc *= dv;
    if (bias) acc += bias[lane];
    if (do_relu) acc = fmaxf(acc, 0.f);
    if (post_scale) acc *= dv;
    out[(size_t)wid * 64 + lane] = bf16_of(acc);
}

// ---- Mean pool, chunk-parallel (bf16 input, fp32 accum) -----------------

__global__ void k_pool(const bfu* __restrict__ G, const int* __restrict__ batch,
                       float* __restrict__ Psum, int n) {
    int base = blockIdx.x * 256;
    int lane = threadIdx.x & 63, rg = threadIdx.x >> 6;
    int lim = min(base + 256, n);
    int cur = -1;
    float acc = 0.f;
    for (int r = base + rg; r < lim; r += 4) {
        int g = batch[r];
        if (g != cur) {
            if (cur >= 0) atomicAdd(&Psum[cur * 64 + lane], acc);
            cur = g;
            acc = 0.f;
        }
        acc += f_of_bf16(G[(size_t)r * 64 + lane]);
    }
    if (cur >= 0) atomicAdd(&Psum[cur * 64 + lane], acc);
}

// ---- mean + pooled@W3 + b3 + log_softmax --------------------------------

__global__ void k_final(const float* __restrict__ Psum, const int* __restrict__ batch,
                        int n, const float* __restrict__ W3, const float* __restrict__ b3,
                        float* __restrict__ out, int ng) {
    __shared__ float P[64 * 64];
    __shared__ float s[64][NC];
    __shared__ float lse[64];
    __shared__ float invc[64];
    int t = threadIdx.x;
    if (t < ng) {
        int lo = lower_bound_i(batch, n, t);
        int hi = lower_bound_i(batch, n, t + 1);
        invc[t] = 1.f / (float)max(hi - lo, 1);
    }
    __syncthreads();
    for (int i = t; i < ng * 64; i += blockDim.x) P[i] = Psum[i] * invc[i >> 6];
    __syncthreads();
    if (t < ng * NC) {
        int g = t / NC, c = t % NC;
        float acc = b3[c];
        for (int k = 0; k < 64; k++) acc += P[g * 64 + k] * W3[k * NC + c];
        s[g][c] = acc;
    }
    __syncthreads();
    if (t < ng) {
        float m = -1e30f;
        for (int c = 0; c < NC; c++) m = fmaxf(m, s[t][c]);
        float sum = 0.f;
        for (int c = 0; c < NC; c++) sum += expf(s[t][c] - m);
        lse[t] = m + logf(sum);
    }
    __syncthreads();
    if (t < ng * NC) {
        int g = t / NC, c = t % NC;
        out[t] = s[g][c] - lse[g];
    }
}

// ---- launch -------------------------------------------------------------

extern "C" void kernel_launch(void* const* d_in, const int* in_sizes, int n_in,
                              void* d_out, int out_size, void* d_ws, size_t ws_size,
                              hipStream_t stream) {
    const float* x     = (const float*)d_in[0];
    const int*   ei    = (const int*)  d_in[1];
    const int*   batch = (const int*)  d_in[2];
    const float* W1    = (const float*)d_in[3];
    const float* b1    = (const float*)d_in[4];
    const float* W2    = (const float*)d_in[5];
    const float* b2    = (const float*)d_in[6];
    const float* W3    = (const float*)d_in[7];
    const float* b3    = (const float*)d_in[8];
    float*       out   = (float*)d_out;

    const int NN = in_sizes[0] / IN_CH;   // 100000
    const int E  = in_sizes[1] / 2;       // 1600000
    const int NG = out_size / NC;         // 64
    const int nbuck = (NN + (1 << BSH) - 1) >> BSH;  // 782

    const int* src = ei;
    const int* dst = ei + E;

    char* ws = (char*)d_ws;
    size_t off = 0;
    auto carve = [&](size_t bytes) -> char* {
        char* p = ws + off;
        off = (off + bytes + 255) & ~(size_t)255;
        return p;
    };
    int*   cnt    = (int*)  carve((size_t)NN * 4);
    int*   rowptr = (int*)  carve((size_t)(NN + 1) * 4);
    float* dinv   = (float*)carve((size_t)NN * 4);
    int*   bsum   = (int*)  carve(4096);
    int*   bsumG  = (int*)  carve(4096);
    int*   bstart = (int*)  carve((size_t)(nbuck + 1) * 4);
    int*   Gh     = (int*)  carve((size_t)nbuck * NBLK * 4);
    int*   meta   = (int*)  carve((size_t)E * 4);
    bfu*   bufA   = (bfu*)  carve((size_t)NN * HID * 2);
    bfu*   bufB   = (bfu*)  carve((size_t)NN * HID * 2);
    float* Psum   = (float*)carve((size_t)NG * HID * 4);
    (void)ws_size;

    int2* packed = (int2*)bufA;   // E*8 = 12.8 MB aliases bufA (dead until gemm1)

    const int nbN  = (NN + 255) / 256;          // 391
    const int nG   = nbuck * NBLK;              // 200192
    const int nbGh = (nG + 255) / 256;          // 782
    const int chnk = (E + NBLK - 1) / NBLK;
    const size_t lds_h = (size_t)nbuck * 4;

    hipMemsetAsync(cnt, 0, (size_t)NN * 4, stream);
    hipMemsetAsync(Psum, 0, (size_t)NG * HID * 4, stream);
    k_count_hist<<<NBLK, 256, lds_h, stream>>>(dst, cnt, Gh, E, nbuck, chnk);
    // rowptr = exclusive-scan(cnt)
    k_scan1<<<nbN, 256, 0, stream>>>(cnt, rowptr, bsum, NN);
    k_scan2<<<1, 1024, 0, stream>>>(bsum, nbN);
    k_scan3<<<nbN, 256, 0, stream>>>(rowptr, bsum, NN, E);
    k_dinv <<<nbN, 256, 0, stream>>>(cnt, dinv, NN);
    // Gh = exclusive-scan(Gh) (hierarchical), bstart extracted
    k_scan1<<<nbGh, 256, 0, stream>>>(Gh, Gh, bsumG, nG);
    k_scan2<<<1, 1024, 0, stream>>>(bsumG, nbGh);
    k_scan3g<<<nbGh, 256, 0, stream>>>(Gh, bsumG, bstart, nG, nbuck, E);

    k_partB <<<NBLK, 256, lds_h, stream>>>(src, dst, Gh, packed, E, nbuck, chnk);
    k_placeC<<<nbuck, 256, 0, stream>>>(packed, bstart, rowptr, meta, NN);

    const int nbG = (NN + 127) / 128;
    const int nbA = ((size_t)NN * 64 + 255) / 256;

    // layer 1: G1 = dinv*(x@W1) ; H1 = relu(dinv*(G1[v]+sum G1[src]) + b1)
    k_gemm<IN_CH, false><<<nbG, 256, 0, stream>>>(x, W1, dinv, bufA, NN);
    k_agg<<<nbA, 256, 0, stream>>>(bufA, meta, rowptr, dinv, b1, bufB, NN, 1, 0);
    // layer 2
    k_gemm<HID, true><<<nbG, 256, 0, stream>>>(bufB, W2, dinv, bufA, NN);
    k_agg<<<nbA, 256, 0, stream>>>(bufA, meta, rowptr, dinv, b2, bufB, NN, 1, 1);
    // layer 3 (reordered) + pool + head
    k_agg<<<nbA, 256, 0, stream>>>(bufB, meta, rowptr, dinv, nullptr, bufA, NN, 0, 0);
    k_pool<<<nbN, 256, 0, stream>>>(bufA, batch, Psum, NN);
    k_final<<<1, 640, 0, stream>>>(Psum, batch, NN, W3, b3, out, NG);
}

// Round 8
// 418.692 us; speedup vs baseline: 1.9306x; 1.1666x over previous
//
#include <hip/hip_runtime.h>

#define IN_CH 128
#define HID   64
#define NC    10
#define BSH   8       // 256 nodes per bucket
#define NBLK  256     // partition blocks

typedef unsigned short bfu;

static __device__ __forceinline__ bfu bf16_of(float f) {
    unsigned u = __float_as_uint(f);
    unsigned r = (u + 0x7FFF + ((u >> 16) & 1)) >> 16;   // RNE
    return (bfu)r;
}
static __device__ __forceinline__ float f_of_bf16(bfu u) {
    return __uint_as_float(((unsigned)u) << 16);
}

__device__ __forceinline__ int lower_bound_i(const int* a, int n, int v) {
    int lo = 0, hi = n;
    while (lo < hi) { int mid = (lo + hi) >> 1; if (a[mid] < v) lo = mid + 1; else hi = mid; }
    return lo;
}

// ---- bucket histogram (LDS only — no global atomics) --------------------

__global__ __launch_bounds__(1024) void k_hist(const int* __restrict__ dst,
                                               int* __restrict__ Gh,
                                               int E, int nbuck, int chunk) {
    __shared__ int h[512];
    for (int b = threadIdx.x; b < nbuck; b += blockDim.x) h[b] = 0;
    __syncthreads();
    int base = blockIdx.x * chunk;
    int lim  = min(base + chunk, E);
    for (int e = base + threadIdx.x; e < lim; e += blockDim.x)
        atomicAdd(&h[dst[e] >> BSH], 1);
    __syncthreads();
    for (int b = threadIdx.x; b < nbuck; b += blockDim.x)
        Gh[b * NBLK + blockIdx.x] = h[b];
}

// ---- hierarchical exclusive scan pieces ---------------------------------

__global__ void k_scan1(const int* __restrict__ cnt, int* __restrict__ excl,
                        int* __restrict__ bsum, int n) {
    __shared__ int s[256];
    int i = blockIdx.x * 256 + threadIdx.x;
    int v = (i < n) ? cnt[i] : 0;
    s[threadIdx.x] = v;
    __syncthreads();
    for (int off = 1; off < 256; off <<= 1) {
        int t = (threadIdx.x >= off) ? s[threadIdx.x - off] : 0;
        __syncthreads();
        s[threadIdx.x] += t;
        __syncthreads();
    }
    if (i < n) excl[i] = s[threadIdx.x] - v;
    if (threadIdx.x == 255) bsum[blockIdx.x] = s[255];
}

__global__ void k_scan2(int* __restrict__ bsum, int nb) {
    __shared__ int s[1024];
    int v = (threadIdx.x < nb) ? bsum[threadIdx.x] : 0;
    s[threadIdx.x] = v;
    __syncthreads();
    for (int off = 1; off < 1024; off <<= 1) {
        int t = (threadIdx.x >= off) ? s[threadIdx.x - off] : 0;
        __syncthreads();
        s[threadIdx.x] += t;
        __syncthreads();
    }
    if (threadIdx.x < nb) bsum[threadIdx.x] = s[threadIdx.x] - v;
}

// add block offsets to Gh and extract bucket starts
__global__ void k_scan3g(int* __restrict__ Gh, const int* __restrict__ bsum,
                         int* __restrict__ bstart, int n, int nbuck, int E) {
    int i = blockIdx.x * 256 + threadIdx.x;
    if (i < n) {
        int v = Gh[i] + bsum[i >> 8];
        Gh[i] = v;
        if ((i & (NBLK - 1)) == 0) bstart[i / NBLK] = v;
    }
    if (i == 0) bstart[nbuck] = E;
}

// ---- partB: scatter (src,dst) into bucket-grouped order -----------------

__global__ __launch_bounds__(1024) void k_partB(const int* __restrict__ src,
                                                const int* __restrict__ dst,
                                                const int* __restrict__ Gh,
                                                int2* __restrict__ packed,
                                                int E, int nbuck, int chunk) {
    __shared__ int cur[512];
    for (int b = threadIdx.x; b < nbuck; b += blockDim.x)
        cur[b] = Gh[b * NBLK + blockIdx.x];
    __syncthreads();
    int base = blockIdx.x * chunk;
    int lim  = min(base + chunk, E);
    for (int e = base + threadIdx.x; e < lim; e += blockDim.x) {
        int d = dst[e], s = src[e];
        int pos = atomicAdd(&cur[d >> BSH], 1);
        packed[pos] = make_int2(s, d);
    }
}

// ---- placeC: per bucket — node histogram -> rowptr + dinv + meta --------

__global__ __launch_bounds__(512) void k_placeC(const int2* __restrict__ packed,
                                                const int* __restrict__ bstart,
                                                int* __restrict__ rowptr,
                                                float* __restrict__ dinv,
                                                int* __restrict__ meta,
                                                int nn, int E, int nbuck) {
    __shared__ int hist[256];
    __shared__ int scn[256];
    __shared__ int cur[256];
    int tid = threadIdx.x;
    int b   = blockIdx.x;
    int nb0 = b << BSH;
    int nnb = min(1 << BSH, nn - nb0);
    if (tid < 256) hist[tid] = 0;
    __syncthreads();
    int lo = bstart[b], hi = bstart[b + 1];
    // pass 1: per-node degree within bucket
    for (int e = lo + tid; e < hi; e += blockDim.x)
        atomicAdd(&hist[packed[e].y - nb0], 1);
    __syncthreads();
    // 256-entry inclusive scan (Hillis-Steele), all threads hit barriers
    if (tid < 256) scn[tid] = hist[tid];
    __syncthreads();
    for (int off = 1; off < 256; off <<= 1) {
        int t = 0;
        if (tid < 256 && tid >= off) t = scn[tid - off];
        __syncthreads();
        if (tid < 256) scn[tid] += t;
        __syncthreads();
    }
    if (tid < nnb) {
        int rp = lo + scn[tid] - hist[tid];   // bstart + local exclusive
        rowptr[nb0 + tid] = rp;
        cur[tid] = rp;
        dinv[nb0 + tid] = rsqrtf((float)(hist[tid] + 1));  // +1 self loop
    }
    if (b == nbuck - 1 && tid == 0) rowptr[nn] = E;
    __syncthreads();
    // pass 2: place src into CSR slots (scatter span = this bucket's region)
    for (int e = lo + tid; e < hi; e += blockDim.x) {
        int2 p = packed[e];
        int pos = atomicAdd(&cur[p.y - nb0], 1);
        meta[pos] = p.x;
    }
}

// ---- Dense X@W + dinv-scaled bf16 epilogue ------------------------------

template <int K, bool IN_BF16>
__global__ __launch_bounds__(256) void k_gemm(const void* __restrict__ Xv,
                                              const float* __restrict__ W,
                                              const float* __restrict__ dinv,
                                              bfu* __restrict__ G, int n) {
    __shared__ float4 xs4[128][8];
    __shared__ float4 ws4[32][16];
    int tid  = threadIdx.x;
    int row0 = blockIdx.x * 128;
    int cg = tid & 15, rg = tid >> 4;
    float acc[8][4];
#pragma unroll
    for (int r = 0; r < 8; r++)
#pragma unroll
        for (int c = 0; c < 4; c++) acc[r][c] = 0.f;

    for (int k0 = 0; k0 < K; k0 += 32) {
        int sr = tid >> 3, f4 = tid & 7;
#pragma unroll
        for (int i = 0; i < 4; i++) {
            int row  = sr + i * 32;
            int grow = row0 + row;
            float4 v = make_float4(0.f, 0.f, 0.f, 0.f);
            if (grow < n) {
                if (IN_BF16) {
                    const bfu* X = (const bfu*)Xv;
                    ushort4 u = *(const ushort4*)&X[(size_t)grow * K + k0 + f4 * 4];
                    v = make_float4(f_of_bf16(u.x), f_of_bf16(u.y),
                                    f_of_bf16(u.z), f_of_bf16(u.w));
                } else {
                    const float* X = (const float*)Xv;
                    v = *(const float4*)&X[(size_t)grow * K + k0 + f4 * 4];
                }
            }
            xs4[row][f4 ^ ((row >> 3) & 3)] = v;
        }
        {
            const float4* Wp = (const float4*)&W[(size_t)k0 * 64];
            int j0 = tid, j1 = tid + 256;
            ws4[j0 >> 4][j0 & 15] = Wp[j0];
            ws4[j1 >> 4][j1 & 15] = Wp[j1];
        }
        __syncthreads();
#pragma unroll
        for (int k4 = 0; k4 < 8; k4++) {
            float4 av[8];
#pragma unroll
            for (int r = 0; r < 8; r++) av[r] = xs4[rg * 8 + r][k4 ^ (rg & 3)];
            float4 wv[4];
#pragma unroll
            for (int kk = 0; kk < 4; kk++) wv[kk] = ws4[k4 * 4 + kk][cg];
#pragma unroll
            for (int kk = 0; kk < 4; kk++) {
#pragma unroll
                for (int r = 0; r < 8; r++) {
                    float a = ((const float*)&av[r])[kk];
                    acc[r][0] += a * wv[kk].x;
                    acc[r][1] += a * wv[kk].y;
                    acc[r][2] += a * wv[kk].z;
                    acc[r][3] += a * wv[kk].w;
                }
            }
        }
        __syncthreads();
    }
#pragma unroll
    for (int r = 0; r < 8; r++) {
        int row = row0 + rg * 8 + r;
        if (row < n) {
            float dv = dinv[row];
            ushort4 o;
            o.x = bf16_of(acc[r][0] * dv);
            o.y = bf16_of(acc[r][1] * dv);
            o.z = bf16_of(acc[r][2] * dv);
            o.w = bf16_of(acc[r][3] * dv);
            *(ushort4*)&G[(size_t)row * 64 + cg * 4] = o;
        }
    }
}

// ---- CSR gather agg: wave/node, lane=col, branchless 16-deep MLP --------

__global__ void k_agg(const bfu* __restrict__ G, const int* __restrict__ meta,
                      const int* __restrict__ rowptr, const float* __restrict__ dinv,
                      const float* __restrict__ bias, bfu* __restrict__ out,
                      int n, int do_relu, int post_scale) {
    int wid  = (blockIdx.x * blockDim.x + threadIdx.x) >> 6;
    int lane = threadIdx.x & 63;
    if (wid >= n) return;
    int beg = rowptr[wid], end = rowptr[wid + 1];
    float a[8];
    a[0] = f_of_bf16(G[(size_t)wid * 64 + lane]);  // self loop (pre-scaled)
#pragma unroll
    for (int j = 1; j < 8; j++) a[j] = 0.f;
    for (int e = beg; e < end; e += 16) {
        int m[16];
#pragma unroll
        for (int j = 0; j < 16; j++) {
            int ej = e + j;
            m[j] = meta[(ej < end) ? ej : beg];   // branchless clamp
        }
#pragma unroll
        for (int j = 0; j < 16; j++) {
            float v = f_of_bf16(G[(size_t)m[j] * 64 + lane]);
            a[j & 7] += (e + j < end) ? v : 0.f;
        }
    }
    float acc = ((a[0] + a[1]) + (a[2] + a[3])) + ((a[4] + a[5]) + (a[6] + a[7]));
    float dv = dinv[wid];
    acc *= dv;
    if (bias) acc += bias[lane];
    if (do_relu) acc = fmaxf(acc, 0.f);
    if (post_scale) acc *= dv;
    out[(size_t)wid * 64 + lane] = bf16_of(acc);
}

// ---- Mean pool, chunk-parallel (bf16 input, fp32 accum) -----------------

__global__ void k_pool(const bfu* __restrict__ G, const int* __restrict__ batch,
                       float* __restrict__ Psum, int n) {
    int base = blockIdx.x * 256;
    int lane = threadIdx.x & 63, rg = threadIdx.x >> 6;
    int lim = min(base + 256, n);
    int cur = -1;
    float acc = 0.f;
    for (int r = base + rg; r < lim; r += 4) {
        int g = batch[r];
        if (g != cur) {
            if (cur >= 0) atomicAdd(&Psum[cur * 64 + lane], acc);
            cur = g;
            acc = 0.f;
        }
        acc += f_of_bf16(G[(size_t)r * 64 + lane]);
    }
    if (cur >= 0) atomicAdd(&Psum[cur * 64 + lane], acc);
}

// ---- mean + pooled@W3 + b3 + log_softmax --------------------------------

__global__ void k_final(const float* __restrict__ Psum, const int* __restrict__ batch,
                        int n, const float* __restrict__ W3, const float* __restrict__ b3,
                        float* __restrict__ out, int ng) {
    __shared__ float P[64 * 64];
    __shared__ float s[64][NC];
    __shared__ float lse[64];
    __shared__ float invc[64];
    int t = threadIdx.x;
    if (t < ng) {
        int lo = lower_bound_i(batch, n, t);
        int hi = lower_bound_i(batch, n, t + 1);
        invc[t] = 1.f / (float)max(hi - lo, 1);
    }
    __syncthreads();
    for (int i = t; i < ng * 64; i += blockDim.x) P[i] = Psum[i] * invc[i >> 6];
    __syncthreads();
    if (t < ng * NC) {
        int g = t / NC, c = t % NC;
        float acc = b3[c];
        for (int k = 0; k < 64; k++) acc += P[g * 64 + k] * W3[k * NC + c];
        s[g][c] = acc;
    }
    __syncthreads();
    if (t < ng) {
        float m = -1e30f;
        for (int c = 0; c < NC; c++) m = fmaxf(m, s[t][c]);
        float sum = 0.f;
        for (int c = 0; c < NC; c++) sum += expf(s[t][c] - m);
        lse[t] = m + logf(sum);
    }
    __syncthreads();
    if (t < ng * NC) {
        int g = t / NC, c = t % NC;
        out[t] = s[g][c] - lse[g];
    }
}

// ---- launch -------------------------------------------------------------

extern "C" void kernel_launch(void* const* d_in, const int* in_sizes, int n_in,
                              void* d_out, int out_size, void* d_ws, size_t ws_size,
                              hipStream_t stream) {
    const float* x     = (const float*)d_in[0];
    const int*   ei    = (const int*)  d_in[1];
    const int*   batch = (const int*)  d_in[2];
    const float* W1    = (const float*)d_in[3];
    const float* b1    = (const float*)d_in[4];
    const float* W2    = (const float*)d_in[5];
    const float* b2    = (const float*)d_in[6];
    const float* W3    = (const float*)d_in[7];
    const float* b3    = (const float*)d_in[8];
    float*       out   = (float*)d_out;

    const int NN = in_sizes[0] / IN_CH;   // 100000
    const int E  = in_sizes[1] / 2;       // 1600000
    const int NG = out_size / NC;         // 64
    const int nbuck = (NN + (1 << BSH) - 1) >> BSH;  // 391

    const int* src = ei;
    const int* dst = ei + E;

    char* ws = (char*)d_ws;
    size_t off = 0;
    auto carve = [&](size_t bytes) -> char* {
        char* p = ws + off;
        off = (off + bytes + 255) & ~(size_t)255;
        return p;
    };
    int*   rowptr = (int*)  carve((size_t)(NN + 1) * 4);
    float* dinv   = (float*)carve((size_t)NN * 4);
    int*   bsumG  = (int*)  carve(4096);
    int*   bstart = (int*)  carve((size_t)(nbuck + 1) * 4);
    int*   Gh     = (int*)  carve((size_t)nbuck * NBLK * 4);
    int*   meta   = (int*)  carve((size_t)E * 4);
    bfu*   bufA   = (bfu*)  carve((size_t)NN * HID * 2);
    bfu*   bufB   = (bfu*)  carve((size_t)NN * HID * 2);
    float* Psum   = (float*)carve((size_t)NG * HID * 4);
    (void)ws_size;

    int2* packed = (int2*)bufA;   // E*8 = 12.8 MB aliases bufA (dead until gemm1)

    const int nbN  = (NN + 255) / 256;          // 391
    const int nG   = nbuck * NBLK;              // 100096
    const int nbGh = (nG + 255) / 256;          // 391
    const int chnk = (E + NBLK - 1) / NBLK;     // 6250

    hipMemsetAsync(Psum, 0, (size_t)NG * HID * 4, stream);
    k_hist<<<NBLK, 1024, 0, stream>>>(dst, Gh, E, nbuck, chnk);
    k_scan1<<<nbGh, 256, 0, stream>>>(Gh, Gh, bsumG, nG);
    k_scan2<<<1, 1024, 0, stream>>>(bsumG, nbGh);
    k_scan3g<<<nbGh, 256, 0, stream>>>(Gh, bsumG, bstart, nG, nbuck, E);
    k_partB <<<NBLK, 1024, 0, stream>>>(src, dst, Gh, packed, E, nbuck, chnk);
    k_placeC<<<nbuck, 512, 0, stream>>>(packed, bstart, rowptr, dinv, meta, NN, E, nbuck);

    const int nbG = (NN + 127) / 128;
    const int nbA = ((size_t)NN * 64 + 255) / 256;

    // layer 1: G1 = dinv*(x@W1) ; H1 = relu(dinv*(G1[v]+sum G1[src]) + b1)
    k_gemm<IN_CH, false><<<nbG, 256, 0, stream>>>(x, W1, dinv, bufA, NN);
    k_agg<<<nbA, 256, 0, stream>>>(bufA, meta, rowptr, dinv, b1, bufB, NN, 1, 0);
    // layer 2
    k_gemm<HID, true><<<nbG, 256, 0, stream>>>(bufB, W2, dinv, bufA, NN);
    k_agg<<<nbA, 256, 0, stream>>>(bufA, meta, rowptr, dinv, b2, bufB, NN, 1, 1);
    // layer 3 (reordered) + pool + head
    k_agg<<<nbA, 256, 0, stream>>>(bufB, meta, rowptr, dinv, nullptr, bufA, NN, 0, 0);
    k_pool<<<nbN, 256, 0, stream>>>(bufA, batch, Psum, NN);
    k_final<<<1, 640, 0, stream>>>(Psum, batch, NN, W3, b3, out, NG);
}

// Round 9
// 365.682 us; speedup vs baseline: 2.2105x; 1.1450x over previous
//
#include <hip/hip_runtime.h>

#define IN_CH 128
#define HID   64
#define NC    10
#define BSH   8       // 256 nodes per bucket
#define NBLK  256     // partition blocks
#define BPAD  772     // per-bucket meta slack: 3*256 pads + 4 align

typedef unsigned short bfu;

static __device__ __forceinline__ bfu bf16_of(float f) {
    unsigned u = __float_as_uint(f);
    unsigned r = (u + 0x7FFF + ((u >> 16) & 1)) >> 16;   // RNE
    return (bfu)r;
}
static __device__ __forceinline__ float f_of_bf16(bfu u) {
    return __uint_as_float(((unsigned)u) << 16);
}
static __device__ __forceinline__ float f_lo(unsigned d) {   // low bf16 of dword
    return __uint_as_float(d << 16);
}
static __device__ __forceinline__ float f_hi(unsigned d) {   // high bf16 of dword
    return __uint_as_float(d & 0xFFFF0000u);
}

__device__ __forceinline__ int lower_bound_i(const int* a, int n, int v) {
    int lo = 0, hi = n;
    while (lo < hi) { int mid = (lo + hi) >> 1; if (a[mid] < v) lo = mid + 1; else hi = mid; }
    return lo;
}

// ---- bucket histogram (LDS only — no global atomics) --------------------

__global__ __launch_bounds__(1024) void k_hist(const int* __restrict__ dst,
                                               int* __restrict__ Gh,
                                               int E, int nbuck, int chunk) {
    __shared__ int h[512];
    for (int b = threadIdx.x; b < nbuck; b += blockDim.x) h[b] = 0;
    __syncthreads();
    int base = blockIdx.x * chunk;
    int lim  = min(base + chunk, E);
    for (int e = base + threadIdx.x; e < lim; e += blockDim.x)
        atomicAdd(&h[dst[e] >> BSH], 1);
    __syncthreads();
    for (int b = threadIdx.x; b < nbuck; b += blockDim.x)
        Gh[b * NBLK + blockIdx.x] = h[b];
}

// ---- hierarchical exclusive scan pieces ---------------------------------

__global__ void k_scan1(const int* __restrict__ cnt, int* __restrict__ excl,
                        int* __restrict__ bsum, int n) {
    __shared__ int s[256];
    int i = blockIdx.x * 256 + threadIdx.x;
    int v = (i < n) ? cnt[i] : 0;
    s[threadIdx.x] = v;
    __syncthreads();
    for (int off = 1; off < 256; off <<= 1) {
        int t = (threadIdx.x >= off) ? s[threadIdx.x - off] : 0;
        __syncthreads();
        s[threadIdx.x] += t;
        __syncthreads();
    }
    if (i < n) excl[i] = s[threadIdx.x] - v;
    if (threadIdx.x == 255) bsum[blockIdx.x] = s[255];
}

__global__ void k_scan2(int* __restrict__ bsum, int nb) {
    __shared__ int s[1024];
    int v = (threadIdx.x < nb) ? bsum[threadIdx.x] : 0;
    s[threadIdx.x] = v;
    __syncthreads();
    for (int off = 1; off < 1024; off <<= 1) {
        int t = (threadIdx.x >= off) ? s[threadIdx.x - off] : 0;
        __syncthreads();
        s[threadIdx.x] += t;
        __syncthreads();
    }
    if (threadIdx.x < nb) bsum[threadIdx.x] = s[threadIdx.x] - v;
}

// add block offsets to Gh and extract bucket starts
__global__ void k_scan3g(int* __restrict__ Gh, const int* __restrict__ bsum,
                         int* __restrict__ bstart, int n, int nbuck, int E) {
    int i = blockIdx.x * 256 + threadIdx.x;
    if (i < n) {
        int v = Gh[i] + bsum[i >> 8];
        Gh[i] = v;
        if ((i & (NBLK - 1)) == 0) bstart[i / NBLK] = v;
    }
    if (i == 0) bstart[nbuck] = E;
}

// ---- partB: scatter (src,dst) into bucket-grouped order -----------------

__global__ __launch_bounds__(1024) void k_partB(const int* __restrict__ src,
                                                const int* __restrict__ dst,
                                                const int* __restrict__ Gh,
                                                int2* __restrict__ packed,
                                                int E, int nbuck, int chunk) {
    __shared__ int cur[512];
    for (int b = threadIdx.x; b < nbuck; b += blockDim.x)
        cur[b] = Gh[b * NBLK + blockIdx.x];
    __syncthreads();
    int base = blockIdx.x * chunk;
    int lim  = min(base + chunk, E);
    for (int e = base + threadIdx.x; e < lim; e += blockDim.x) {
        int d = dst[e], s = src[e];
        int pos = atomicAdd(&cur[d >> BSH], 1);
        packed[pos] = make_int2(s, d);
    }
}

// ---- placeC: per bucket — histogram -> PADDED rowptr/rend + dinv + meta -
// Each node's meta segment is padded to a multiple of 4 with dummy index nn
// (whose G-row is all zeros), so k_agg needs no masking at all.

__global__ __launch_bounds__(512) void k_placeC(const int2* __restrict__ packed,
                                                const int* __restrict__ bstart,
                                                int* __restrict__ rowptr,
                                                int* __restrict__ rend,
                                                float* __restrict__ dinv,
                                                int* __restrict__ meta,
                                                int nn, int nbuck) {
    __shared__ int hist[256];
    __shared__ int scn[256];
    __shared__ int cur[256];
    int tid = threadIdx.x;
    int b   = blockIdx.x;
    int nb0 = b << BSH;
    int nnb = min(1 << BSH, nn - nb0);
    if (tid < 256) hist[tid] = 0;
    __syncthreads();
    int lo = bstart[b], hi = bstart[b + 1];
    // pass 1: per-node degree within bucket
    for (int e = lo + tid; e < hi; e += blockDim.x)
        atomicAdd(&hist[packed[e].y - nb0], 1);
    __syncthreads();
    // inclusive scan of padded degrees (Hillis-Steele, 256 entries)
    int pd = 0;
    if (tid < 256) { pd = (hist[tid] + 3) & ~3; scn[tid] = pd; }
    __syncthreads();
    for (int off = 1; off < 256; off <<= 1) {
        int t = 0;
        if (tid < 256 && tid >= off) t = scn[tid - off];
        __syncthreads();
        if (tid < 256) scn[tid] += t;
        __syncthreads();
    }
    int meta0 = ((lo + 3) & ~3) + BPAD * b;   // aligned bucket meta start
    if (tid < nnb) {
        int rp = meta0 + scn[tid] - pd;       // padded exclusive
        rowptr[nb0 + tid] = rp;
        rend[nb0 + tid]   = rp + pd;
        cur[tid] = rp;
        dinv[nb0 + tid] = rsqrtf((float)(hist[tid] + 1));  // +1 self loop
        for (int k = hist[tid]; k < pd; k++) meta[rp + k] = nn;  // pads
    }
    __syncthreads();
    // pass 2: place src into padded CSR slots
    for (int e = lo + tid; e < hi; e += blockDim.x) {
        int2 p = packed[e];
        int pos = atomicAdd(&cur[p.y - nb0], 1);
        meta[pos] = p.x;
    }
}

// ---- Dense X@W + dinv-scaled bf16 epilogue ------------------------------

template <int K, bool IN_BF16>
__global__ __launch_bounds__(256) void k_gemm(const void* __restrict__ Xv,
                                              const float* __restrict__ W,
                                              const float* __restrict__ dinv,
                                              bfu* __restrict__ G, int n) {
    __shared__ float4 xs4[128][8];
    __shared__ float4 ws4[32][16];
    int tid  = threadIdx.x;
    int row0 = blockIdx.x * 128;
    int cg = tid & 15, rg = tid >> 4;
    float acc[8][4];
#pragma unroll
    for (int r = 0; r < 8; r++)
#pragma unroll
        for (int c = 0; c < 4; c++) acc[r][c] = 0.f;

    for (int k0 = 0; k0 < K; k0 += 32) {
        int sr = tid >> 3, f4 = tid & 7;
#pragma unroll
        for (int i = 0; i < 4; i++) {
            int row  = sr + i * 32;
            int grow = row0 + row;
            float4 v = make_float4(0.f, 0.f, 0.f, 0.f);
            if (grow < n) {
                if (IN_BF16) {
                    const bfu* X = (const bfu*)Xv;
                    ushort4 u = *(const ushort4*)&X[(size_t)grow * K + k0 + f4 * 4];
                    v = make_float4(f_of_bf16(u.x), f_of_bf16(u.y),
                                    f_of_bf16(u.z), f_of_bf16(u.w));
                } else {
                    const float* X = (const float*)Xv;
                    v = *(const float4*)&X[(size_t)grow * K + k0 + f4 * 4];
                }
            }
            xs4[row][f4 ^ ((row >> 3) & 3)] = v;
        }
        {
            const float4* Wp = (const float4*)&W[(size_t)k0 * 64];
            int j0 = tid, j1 = tid + 256;
            ws4[j0 >> 4][j0 & 15] = Wp[j0];
            ws4[j1 >> 4][j1 & 15] = Wp[j1];
        }
        __syncthreads();
#pragma unroll
        for (int k4 = 0; k4 < 8; k4++) {
            float4 av[8];
#pragma unroll
            for (int r = 0; r < 8; r++) av[r] = xs4[rg * 8 + r][k4 ^ (rg & 3)];
            float4 wv[4];
#pragma unroll
            for (int kk = 0; kk < 4; kk++) wv[kk] = ws4[k4 * 4 + kk][cg];
#pragma unroll
            for (int kk = 0; kk < 4; kk++) {
#pragma unroll
                for (int r = 0; r < 8; r++) {
                    float a = ((const float*)&av[r])[kk];
                    acc[r][0] += a * wv[kk].x;
                    acc[r][1] += a * wv[kk].y;
                    acc[r][2] += a * wv[kk].z;
                    acc[r][3] += a * wv[kk].w;
                }
            }
        }
        __syncthreads();
    }
#pragma unroll
    for (int r = 0; r < 8; r++) {
        int row = row0 + rg * 8 + r;
        if (row < n) {
            float dv = dinv[row];
            ushort4 o;
            o.x = bf16_of(acc[r][0] * dv);
            o.y = bf16_of(acc[r][1] * dv);
            o.z = bf16_of(acc[r][2] * dv);
            o.w = bf16_of(acc[r][3] * dv);
            *(ushort4*)&G[(size_t)row * 64 + cg * 4] = o;
        }
    }
}

// ---- CSR gather agg: wave/node, 16 lanes x 4 cols, 4 edge-quads ---------
// Padded meta (multiple of 4, dummy=zero-row) -> maskless inner loop.
// equad q processes edge groups [beg+4q, +4) stepping 16; int4 meta load +
// 4x uint2 (4-col) gathers per group. Cross-equad shfl reduction at end.

__global__ void k_agg(const bfu* __restrict__ G, const int* __restrict__ meta,
                      const int* __restrict__ rowptr, const int* __restrict__ rend,
                      const float* __restrict__ dinv, const float* __restrict__ bias,
                      bfu* __restrict__ out, int n, int do_relu, int post_scale) {
    int wid  = (blockIdx.x * blockDim.x + threadIdx.x) >> 6;
    int lane = threadIdx.x & 63;
    if (wid >= n) return;
    int col4 = lane & 15, equad = lane >> 4;
    const uint2* G2 = (const uint2*)G;          // row = 16 x uint2
    int beg = rowptr[wid], pend = rend[wid];
    float a0 = 0.f, a1 = 0.f, a2 = 0.f, a3 = 0.f;
    for (int e = beg + 4 * equad; e < pend; e += 16) {
        int4 m = *(const int4*)&meta[e];
        uint2 d0 = G2[(size_t)m.x * 16 + col4];
        uint2 d1 = G2[(size_t)m.y * 16 + col4];
        uint2 d2 = G2[(size_t)m.z * 16 + col4];
        uint2 d3 = G2[(size_t)m.w * 16 + col4];
        a0 += f_lo(d0.x) + f_lo(d1.x) + f_lo(d2.x) + f_lo(d3.x);
        a1 += f_hi(d0.x) + f_hi(d1.x) + f_hi(d2.x) + f_hi(d3.x);
        a2 += f_lo(d0.y) + f_lo(d1.y) + f_lo(d2.y) + f_lo(d3.y);
        a3 += f_hi(d0.y) + f_hi(d1.y) + f_hi(d2.y) + f_hi(d3.y);
    }
    // reduce across equads (lanes l, l+16, l+32, l+48 -> lane l)
    a0 += __shfl_down(a0, 32, 64); a1 += __shfl_down(a1, 32, 64);
    a2 += __shfl_down(a2, 32, 64); a3 += __shfl_down(a3, 32, 64);
    a0 += __shfl_down(a0, 16, 64); a1 += __shfl_down(a1, 16, 64);
    a2 += __shfl_down(a2, 16, 64); a3 += __shfl_down(a3, 16, 64);
    if (equad == 0) {
        uint2 s = G2[(size_t)wid * 16 + col4];   // self loop (pre-scaled)
        a0 += f_lo(s.x); a1 += f_hi(s.x); a2 += f_lo(s.y); a3 += f_hi(s.y);
        float dv = dinv[wid];
        a0 *= dv; a1 *= dv; a2 *= dv; a3 *= dv;
        if (bias) {
            float4 bv = *(const float4*)&bias[col4 * 4];
            a0 += bv.x; a1 += bv.y; a2 += bv.z; a3 += bv.w;
        }
        if (do_relu) {
            a0 = fmaxf(a0, 0.f); a1 = fmaxf(a1, 0.f);
            a2 = fmaxf(a2, 0.f); a3 = fmaxf(a3, 0.f);
        }
        if (post_scale) { a0 *= dv; a1 *= dv; a2 *= dv; a3 *= dv; }
        uint2 o;
        o.x = (unsigned)bf16_of(a0) | ((unsigned)bf16_of(a1) << 16);
        o.y = (unsigned)bf16_of(a2) | ((unsigned)bf16_of(a3) << 16);
        ((uint2*)out)[(size_t)wid * 16 + col4] = o;
    }
}

// ---- Mean pool, chunk-parallel (bf16 input, fp32 accum) -----------------

__global__ void k_pool(const bfu* __restrict__ G, const int* __restrict__ batch,
                       float* __restrict__ Psum, int n) {
    int base = blockIdx.x * 256;
    int lane = threadIdx.x & 63, rg = threadIdx.x >> 6;
    int lim = min(base + 256, n);
    int cur = -1;
    float acc = 0.f;
    for (int r = base + rg; r < lim; r += 4) {
        int g = batch[r];
        if (g != cur) {
            if (cur >= 0) atomicAdd(&Psum[cur * 64 + lane], acc);
            cur = g;
            acc = 0.f;
        }
        acc += f_of_bf16(G[(size_t)r * 64 + lane]);
    }
    if (cur >= 0) atomicAdd(&Psum[cur * 64 + lane], acc);
}

// ---- mean + pooled@W3 + b3 + log_softmax --------------------------------

__global__ void k_final(const float* __restrict__ Psum, const int* __restrict__ batch,
                        int n, const float* __restrict__ W3, const float* __restrict__ b3,
                        float* __restrict__ out, int ng) {
    __shared__ float P[64 * 64];
    __shared__ float s[64][NC];
    __shared__ float lse[64];
    __shared__ float invc[64];
    int t = threadIdx.x;
    if (t < ng) {
        int lo = lower_bound_i(batch, n, t);
        int hi = lower_bound_i(batch, n, t + 1);
        invc[t] = 1.f / (float)max(hi - lo, 1);
    }
    __syncthreads();
    for (int i = t; i < ng * 64; i += blockDim.x) P[i] = Psum[i] * invc[i >> 6];
    __syncthreads();
    if (t < ng * NC) {
        int g = t / NC, c = t % NC;
        float acc = b3[c];
        for (int k = 0; k < 64; k++) acc += P[g * 64 + k] * W3[k * NC + c];
        s[g][c] = acc;
    }
    __syncthreads();
    if (t < ng) {
        float m = -1e30f;
        for (int c = 0; c < NC; c++) m = fmaxf(m, s[t][c]);
        float sum = 0.f;
        for (int c = 0; c < NC; c++) sum += expf(s[t][c] - m);
        lse[t] = m + logf(sum);
    }
    __syncthreads();
    if (t < ng * NC) {
        int g = t / NC, c = t % NC;
        out[t] = s[g][c] - lse[g];
    }
}

// ---- launch -------------------------------------------------------------

extern "C" void kernel_launch(void* const* d_in, const int* in_sizes, int n_in,
                              void* d_out, int out_size, void* d_ws, size_t ws_size,
                              hipStream_t stream) {
    const float* x     = (const float*)d_in[0];
    const int*   ei    = (const int*)  d_in[1];
    const int*   batch = (const int*)  d_in[2];
    const float* W1    = (const float*)d_in[3];
    const float* b1    = (const float*)d_in[4];
    const float* W2    = (const float*)d_in[5];
    const float* b2    = (const float*)d_in[6];
    const float* W3    = (const float*)d_in[7];
    const float* b3    = (const float*)d_in[8];
    float*       out   = (float*)d_out;

    const int NN = in_sizes[0] / IN_CH;   // 100000
    const int E  = in_sizes[1] / 2;       // 1600000
    const int NG = out_size / NC;         // 64
    const int nbuck = (NN + (1 << BSH) - 1) >> BSH;  // 391

    const int* src = ei;
    const int* dst = ei + E;

    char* ws = (char*)d_ws;
    size_t off = 0;
    auto carve = [&](size_t bytes) -> char* {
        char* p = ws + off;
        off = (off + bytes + 255) & ~(size_t)255;
        return p;
    };
    int*   rowptr = (int*)  carve((size_t)NN * 4);
    int*   rend   = (int*)  carve((size_t)NN * 4);
    float* dinv   = (float*)carve((size_t)NN * 4);
    int*   bsumG  = (int*)  carve(4096);
    int*   bstart = (int*)  carve((size_t)(nbuck + 1) * 4);
    int*   Gh     = (int*)  carve((size_t)nbuck * NBLK * 4);
    int*   meta   = (int*)  carve(((size_t)E + (size_t)BPAD * nbuck + 64) * 4);
    bfu*   bufA   = (bfu*)  carve((size_t)(NN + 1) * HID * 2);  // +1 dummy zero row
    bfu*   bufB   = (bfu*)  carve((size_t)(NN + 1) * HID * 2);
    float* Psum   = (float*)carve((size_t)NG * HID * 4);
    (void)ws_size;

    int2* packed = (int2*)bufA;   // E*8 = 12.8 MB fits in bufA's first NN rows

    const int nbN  = (NN + 255) / 256;          // 391
    const int nG   = nbuck * NBLK;              // 100096
    const int nbGh = (nG + 255) / 256;          // 391
    const int chnk = (E + NBLK - 1) / NBLK;     // 6250

    hipMemsetAsync(Psum, 0, (size_t)NG * HID * 4, stream);
    hipMemsetAsync(bufA + (size_t)NN * HID, 0, HID * 2, stream);  // dummy row
    hipMemsetAsync(bufB + (size_t)NN * HID, 0, HID * 2, stream);
    k_hist<<<NBLK, 1024, 0, stream>>>(dst, Gh, E, nbuck, chnk);
    k_scan1<<<nbGh, 256, 0, stream>>>(Gh, Gh, bsumG, nG);
    k_scan2<<<1, 1024, 0, stream>>>(bsumG, nbGh);
    k_scan3g<<<nbGh, 256, 0, stream>>>(Gh, bsumG, bstart, nG, nbuck, E);
    k_partB <<<NBLK, 1024, 0, stream>>>(src, dst, Gh, packed, E, nbuck, chnk);
    k_placeC<<<nbuck, 512, 0, stream>>>(packed, bstart, rowptr, rend, dinv, meta, NN, nbuck);

    const int nbG = (NN + 127) / 128;
    const int nbA = ((size_t)NN * 64 + 255) / 256;

    // layer 1: G1 = dinv*(x@W1) ; H1 = relu(dinv*(G1[v]+sum G1[src]) + b1)
    k_gemm<IN_CH, false><<<nbG, 256, 0, stream>>>(x, W1, dinv, bufA, NN);
    k_agg<<<nbA, 256, 0, stream>>>(bufA, meta, rowptr, rend, dinv, b1, bufB, NN, 1, 0);
    // layer 2
    k_gemm<HID, true><<<nbG, 256, 0, stream>>>(bufB, W2, dinv, bufA, NN);
    k_agg<<<nbA, 256, 0, stream>>>(bufA, meta, rowptr, rend, dinv, b2, bufB, NN, 1, 1);
    // layer 3 (reordered) + pool + head
    k_agg<<<nbA, 256, 0, stream>>>(bufB, meta, rowptr, rend, dinv, nullptr, bufA, NN, 0, 0);
    k_pool<<<nbN, 256, 0, stream>>>(bufA, batch, Psum, NN);
    k_final<<<1, 640, 0, stream>>>(Psum, batch, NN, W3, b3, out, NG);
}

// Round 10
// 331.713 us; speedup vs baseline: 2.4368x; 1.1024x over previous
//
#include <hip/hip_runtime.h>

#define IN_CH 128
#define HID   64
#define NC    10
#define BSH   8       // 256 nodes per bucket
#define NBLK  256     // partition blocks
#define BPAD  772     // per-bucket meta slack: 3*256 pads + 4 align

typedef unsigned short bfu;
typedef __attribute__((ext_vector_type(8))) short bf16x8;
typedef __attribute__((ext_vector_type(4))) float f32x4;

static __device__ __forceinline__ bfu bf16_of(float f) {
    unsigned u = __float_as_uint(f);
    unsigned r = (u + 0x7FFF + ((u >> 16) & 1)) >> 16;   // RNE
    return (bfu)r;
}
static __device__ __forceinline__ float f_of_bf16(bfu u) {
    return __uint_as_float(((unsigned)u) << 16);
}
static __device__ __forceinline__ float f_lo(unsigned d) {   // low bf16 of dword
    return __uint_as_float(d << 16);
}
static __device__ __forceinline__ float f_hi(unsigned d) {   // high bf16 of dword
    return __uint_as_float(d & 0xFFFF0000u);
}

__device__ __forceinline__ int lower_bound_i(const int* a, int n, int v) {
    int lo = 0, hi = n;
    while (lo < hi) { int mid = (lo + hi) >> 1; if (a[mid] < v) lo = mid + 1; else hi = mid; }
    return lo;
}

// ---- bucket histogram (LDS only — no global atomics) --------------------

__global__ __launch_bounds__(1024) void k_hist(const int* __restrict__ dst,
                                               int* __restrict__ Gh,
                                               int E, int nbuck, int chunk) {
    __shared__ int h[512];
    for (int b = threadIdx.x; b < nbuck; b += blockDim.x) h[b] = 0;
    __syncthreads();
    int base = blockIdx.x * chunk;
    int lim  = min(base + chunk, E);
    for (int e = base + threadIdx.x; e < lim; e += blockDim.x)
        atomicAdd(&h[dst[e] >> BSH], 1);
    __syncthreads();
    for (int b = threadIdx.x; b < nbuck; b += blockDim.x)
        Gh[b * NBLK + blockIdx.x] = h[b];
}

// ---- hierarchical exclusive scan pieces ---------------------------------

__global__ void k_scan1(const int* __restrict__ cnt, int* __restrict__ excl,
                        int* __restrict__ bsum, int n) {
    __shared__ int s[256];
    int i = blockIdx.x * 256 + threadIdx.x;
    int v = (i < n) ? cnt[i] : 0;
    s[threadIdx.x] = v;
    __syncthreads();
    for (int off = 1; off < 256; off <<= 1) {
        int t = (threadIdx.x >= off) ? s[threadIdx.x - off] : 0;
        __syncthreads();
        s[threadIdx.x] += t;
        __syncthreads();
    }
    if (i < n) excl[i] = s[threadIdx.x] - v;
    if (threadIdx.x == 255) bsum[blockIdx.x] = s[255];
}

__global__ void k_scan2(int* __restrict__ bsum, int nb) {
    __shared__ int s[1024];
    int v = (threadIdx.x < nb) ? bsum[threadIdx.x] : 0;
    s[threadIdx.x] = v;
    __syncthreads();
    for (int off = 1; off < 1024; off <<= 1) {
        int t = (threadIdx.x >= off) ? s[threadIdx.x - off] : 0;
        __syncthreads();
        s[threadIdx.x] += t;
        __syncthreads();
    }
    if (threadIdx.x < nb) bsum[threadIdx.x] = s[threadIdx.x] - v;
}

// add block offsets to Gh and extract bucket starts
__global__ void k_scan3g(int* __restrict__ Gh, const int* __restrict__ bsum,
                         int* __restrict__ bstart, int n, int nbuck, int E) {
    int i = blockIdx.x * 256 + threadIdx.x;
    if (i < n) {
        int v = Gh[i] + bsum[i >> 8];
        Gh[i] = v;
        if ((i & (NBLK - 1)) == 0) bstart[i / NBLK] = v;
    }
    if (i == 0) bstart[nbuck] = E;
}

// ---- partB: scatter (src,dst) into bucket-grouped order -----------------

__global__ __launch_bounds__(1024) void k_partB(const int* __restrict__ src,
                                                const int* __restrict__ dst,
                                                const int* __restrict__ Gh,
                                                int2* __restrict__ packed,
                                                int E, int nbuck, int chunk) {
    __shared__ int cur[512];
    for (int b = threadIdx.x; b < nbuck; b += blockDim.x)
        cur[b] = Gh[b * NBLK + blockIdx.x];
    __syncthreads();
    int base = blockIdx.x * chunk;
    int lim  = min(base + chunk, E);
    for (int e = base + threadIdx.x; e < lim; e += blockDim.x) {
        int d = dst[e], s = src[e];
        int pos = atomicAdd(&cur[d >> BSH], 1);
        packed[pos] = make_int2(s, d);
    }
}

// ---- placeC: per bucket — histogram -> PADDED rowptr/rend + dinv + meta -

__global__ __launch_bounds__(512) void k_placeC(const int2* __restrict__ packed,
                                                const int* __restrict__ bstart,
                                                int* __restrict__ rowptr,
                                                int* __restrict__ rend,
                                                float* __restrict__ dinv,
                                                int* __restrict__ meta,
                                                int nn, int nbuck) {
    __shared__ int hist[256];
    __shared__ int scn[256];
    __shared__ int cur[256];
    int tid = threadIdx.x;
    int b   = blockIdx.x;
    int nb0 = b << BSH;
    int nnb = min(1 << BSH, nn - nb0);
    if (tid < 256) hist[tid] = 0;
    __syncthreads();
    int lo = bstart[b], hi = bstart[b + 1];
    for (int e = lo + tid; e < hi; e += blockDim.x)
        atomicAdd(&hist[packed[e].y - nb0], 1);
    __syncthreads();
    int pd = 0;
    if (tid < 256) { pd = (hist[tid] + 3) & ~3; scn[tid] = pd; }
    __syncthreads();
    for (int off = 1; off < 256; off <<= 1) {
        int t = 0;
        if (tid < 256 && tid >= off) t = scn[tid - off];
        __syncthreads();
        if (tid < 256) scn[tid] += t;
        __syncthreads();
    }
    int meta0 = ((lo + 3) & ~3) + BPAD * b;   // aligned bucket meta start
    if (tid < nnb) {
        int rp = meta0 + scn[tid] - pd;
        rowptr[nb0 + tid] = rp;
        rend[nb0 + tid]   = rp + pd;
        cur[tid] = rp;
        dinv[nb0 + tid] = rsqrtf((float)(hist[tid] + 1));  // +1 self loop
        for (int k = hist[tid]; k < pd; k++) meta[rp + k] = nn;  // pads
    }
    __syncthreads();
    for (int e = lo + tid; e < hi; e += blockDim.x) {
        int2 p = packed[e];
        int pos = atomicAdd(&cur[p.y - nb0], 1);
        meta[pos] = p.x;
    }
}

// ---- Dense X@W via MFMA bf16 + dinv-scaled bf16 epilogue ----------------
// Block = 4 waves = 64 rows; wave computes 16 rows x 64 cols via 4 N-tiles.
// A frag: A[m=lane&15][k=quad*8+j] read straight from X (row-major).
// B frag: B[k=quad*8+j][n=lane&15] from LDS wt[n][k] (bf16, k-stride K+8:
//   272/144 B row stride = 4-dword bank rotation -> <=2-way, free).
// D frag: col=lane&15, row=quad*4+reg (guide-verified m89/m91).
// Layer-1 fp32 x is packed to bf16 by v_perm truncation (1 instr per pair).

template <int K, bool IN_BF16>
__global__ __launch_bounds__(256) void k_gemm(const void* __restrict__ Xv,
                                              const float* __restrict__ W,
                                              const float* __restrict__ dinv,
                                              bfu* __restrict__ G, int n) {
    constexpr int KS = K + 8;
    __shared__ bfu wt[64 * KS];
    int tid = threadIdx.x;
    for (int i = tid; i < K * 64; i += 256) {     // stage W^T as bf16 (RNE)
        int k = i >> 6, nn2 = i & 63;
        wt[nn2 * KS + k] = bf16_of(W[i]);
    }
    __syncthreads();
    int wave = tid >> 6, lane = tid & 63;
    int m = lane & 15, q = lane >> 4;
    int row0 = blockIdx.x * 64 + wave * 16;
    int rowA = min(row0 + m, n - 1);              // clamp: OOB rows never stored
    f32x4 acc[4] = {{0.f,0.f,0.f,0.f},{0.f,0.f,0.f,0.f},
                    {0.f,0.f,0.f,0.f},{0.f,0.f,0.f,0.f}};
#pragma unroll
    for (int ks = 0; ks < K / 32; ks++) {
        bf16x8 a;
        if (IN_BF16) {
            a = *(const bf16x8*)((const bfu*)Xv + (size_t)rowA * 64 + ks * 32 + q * 8);
        } else {
            const float* xp = (const float*)Xv + (size_t)rowA * K + ks * 32 + q * 8;
            float4 v0 = *(const float4*)xp;
            float4 v1 = *(const float4*)(xp + 4);
            union { unsigned u[4]; bf16x8 v; } cvt;
            cvt.u[0] = __builtin_amdgcn_perm(__float_as_uint(v0.y), __float_as_uint(v0.x), 0x07060302u);
            cvt.u[1] = __builtin_amdgcn_perm(__float_as_uint(v0.w), __float_as_uint(v0.z), 0x07060302u);
            cvt.u[2] = __builtin_amdgcn_perm(__float_as_uint(v1.y), __float_as_uint(v1.x), 0x07060302u);
            cvt.u[3] = __builtin_amdgcn_perm(__float_as_uint(v1.w), __float_as_uint(v1.z), 0x07060302u);
            a = cvt.v;
        }
#pragma unroll
        for (int nt = 0; nt < 4; nt++) {
            bf16x8 b = *(const bf16x8*)&wt[(nt * 16 + m) * KS + ks * 32 + q * 8];
            acc[nt] = __builtin_amdgcn_mfma_f32_16x16x32_bf16(a, b, acc[nt], 0, 0, 0);
        }
    }
#pragma unroll
    for (int r = 0; r < 4; r++) {
        int grow = row0 + q * 4 + r;
        if (grow < n) {
            float dv = dinv[grow];
#pragma unroll
            for (int nt = 0; nt < 4; nt++)
                G[(size_t)grow * 64 + nt * 16 + m] = bf16_of(acc[nt][r] * dv);
        }
    }
}

// ---- CSR gather agg: wave/node, 16 lanes x 4 cols, 4 edge-quads ---------

__global__ void k_agg(const bfu* __restrict__ G, const int* __restrict__ meta,
                      const int* __restrict__ rowptr, const int* __restrict__ rend,
                      const float* __restrict__ dinv, const float* __restrict__ bias,
                      bfu* __restrict__ out, int n, int do_relu, int post_scale) {
    int wid  = (blockIdx.x * blockDim.x + threadIdx.x) >> 6;
    int lane = threadIdx.x & 63;
    if (wid >= n) return;
    int col4 = lane & 15, equad = lane >> 4;
    const uint2* G2 = (const uint2*)G;          // row = 16 x uint2
    int beg = rowptr[wid], pend = rend[wid];
    float a0 = 0.f, a1 = 0.f, a2 = 0.f, a3 = 0.f;
    for (int e = beg + 4 * equad; e < pend; e += 16) {
        int4 m = *(const int4*)&meta[e];
        uint2 d0 = G2[(size_t)m.x * 16 + col4];
        uint2 d1 = G2[(size_t)m.y * 16 + col4];
        uint2 d2 = G2[(size_t)m.z * 16 + col4];
        uint2 d3 = G2[(size_t)m.w * 16 + col4];
        a0 += f_lo(d0.x) + f_lo(d1.x) + f_lo(d2.x) + f_lo(d3.x);
        a1 += f_hi(d0.x) + f_hi(d1.x) + f_hi(d2.x) + f_hi(d3.x);
        a2 += f_lo(d0.y) + f_lo(d1.y) + f_lo(d2.y) + f_lo(d3.y);
        a3 += f_hi(d0.y) + f_hi(d1.y) + f_hi(d2.y) + f_hi(d3.y);
    }
    a0 += __shfl_down(a0, 32, 64); a1 += __shfl_down(a1, 32, 64);
    a2 += __shfl_down(a2, 32, 64); a3 += __shfl_down(a3, 32, 64);
    a0 += __shfl_down(a0, 16, 64); a1 += __shfl_down(a1, 16, 64);
    a2 += __shfl_down(a2, 16, 64); a3 += __shfl_down(a3, 16, 64);
    if (equad == 0) {
        uint2 s = G2[(size_t)wid * 16 + col4];   // self loop (pre-scaled)
        a0 += f_lo(s.x); a1 += f_hi(s.x); a2 += f_lo(s.y); a3 += f_hi(s.y);
        float dv = dinv[wid];
        a0 *= dv; a1 *= dv; a2 *= dv; a3 *= dv;
        if (bias) {
            float4 bv = *(const float4*)&bias[col4 * 4];
            a0 += bv.x; a1 += bv.y; a2 += bv.z; a3 += bv.w;
        }
        if (do_relu) {
            a0 = fmaxf(a0, 0.f); a1 = fmaxf(a1, 0.f);
            a2 = fmaxf(a2, 0.f); a3 = fmaxf(a3, 0.f);
        }
        if (post_scale) { a0 *= dv; a1 *= dv; a2 *= dv; a3 *= dv; }
        uint2 o;
        o.x = (unsigned)bf16_of(a0) | ((unsigned)bf16_of(a1) << 16);
        o.y = (unsigned)bf16_of(a2) | ((unsigned)bf16_of(a3) << 16);
        ((uint2*)out)[(size_t)wid * 16 + col4] = o;
    }
}

// ---- Mean pool, chunk-parallel (bf16 input, fp32 accum) -----------------

__global__ void k_pool(const bfu* __restrict__ G, const int* __restrict__ batch,
                       float* __restrict__ Psum, int n) {
    int base = blockIdx.x * 256;
    int lane = threadIdx.x & 63, rg = threadIdx.x >> 6;
    int lim = min(base + 256, n);
    int cur = -1;
    float acc = 0.f;
    for (int r = base + rg; r < lim; r += 4) {
        int g = batch[r];
        if (g != cur) {
            if (cur >= 0) atomicAdd(&Psum[cur * 64 + lane], acc);
            cur = g;
            acc = 0.f;
        }
        acc += f_of_bf16(G[(size_t)r * 64 + lane]);
    }
    if (cur >= 0) atomicAdd(&Psum[cur * 64 + lane], acc);
}

// ---- mean + pooled@W3 + b3 + log_softmax --------------------------------

__global__ void k_final(const float* __restrict__ Psum, const int* __restrict__ batch,
                        int n, const float* __restrict__ W3, const float* __restrict__ b3,
                        float* __restrict__ out, int ng) {
    __shared__ float P[64 * 64];
    __shared__ float s[64][NC];
    __shared__ float lse[64];
    __shared__ float invc[64];
    int t = threadIdx.x;
    if (t < ng) {
        int lo = lower_bound_i(batch, n, t);
        int hi = lower_bound_i(batch, n, t + 1);
        invc[t] = 1.f / (float)max(hi - lo, 1);
    }
    __syncthreads();
    for (int i = t; i < ng * 64; i += blockDim.x) P[i] = Psum[i] * invc[i >> 6];
    __syncthreads();
    if (t < ng * NC) {
        int g = t / NC, c = t % NC;
        float acc = b3[c];
        for (int k = 0; k < 64; k++) acc += P[g * 64 + k] * W3[k * NC + c];
        s[g][c] = acc;
    }
    __syncthreads();
    if (t < ng) {
        float m = -1e30f;
        for (int c = 0; c < NC; c++) m = fmaxf(m, s[t][c]);
        float sum = 0.f;
        for (int c = 0; c < NC; c++) sum += expf(s[t][c] - m);
        lse[t] = m + logf(sum);
    }
    __syncthreads();
    if (t < ng * NC) {
        int g = t / NC, c = t % NC;
        out[t] = s[g][c] - lse[g];
    }
}

// ---- launch -------------------------------------------------------------

extern "C" void kernel_launch(void* const* d_in, const int* in_sizes, int n_in,
                              void* d_out, int out_size, void* d_ws, size_t ws_size,
                              hipStream_t stream) {
    const float* x     = (const float*)d_in[0];
    const int*   ei    = (const int*)  d_in[1];
    const int*   batch = (const int*)  d_in[2];
    const float* W1    = (const float*)d_in[3];
    const float* b1    = (const float*)d_in[4];
    const float* W2    = (const float*)d_in[5];
    const float* b2    = (const float*)d_in[6];
    const float* W3    = (const float*)d_in[7];
    const float* b3    = (const float*)d_in[8];
    float*       out   = (float*)d_out;

    const int NN = in_sizes[0] / IN_CH;   // 100000
    const int E  = in_sizes[1] / 2;       // 1600000
    const int NG = out_size / NC;         // 64
    const int nbuck = (NN + (1 << BSH) - 1) >> BSH;  // 391

    const int* src = ei;
    const int* dst = ei + E;

    char* ws = (char*)d_ws;
    size_t off = 0;
    auto carve = [&](size_t bytes) -> char* {
        char* p = ws + off;
        off = (off + bytes + 255) & ~(size_t)255;
        return p;
    };
    int*   rowptr = (int*)  carve((size_t)NN * 4);
    int*   rend   = (int*)  carve((size_t)NN * 4);
    float* dinv   = (float*)carve((size_t)NN * 4);
    int*   bsumG  = (int*)  carve(4096);
    int*   bstart = (int*)  carve((size_t)(nbuck + 1) * 4);
    int*   Gh     = (int*)  carve((size_t)nbuck * NBLK * 4);
    int*   meta   = (int*)  carve(((size_t)E + (size_t)BPAD * nbuck + 64) * 4);
    bfu*   bufA   = (bfu*)  carve((size_t)(NN + 1) * HID * 2);  // +1 dummy zero row
    bfu*   bufB   = (bfu*)  carve((size_t)(NN + 1) * HID * 2);
    float* Psum   = (float*)carve((size_t)NG * HID * 4);
    (void)ws_size;

    int2* packed = (int2*)bufA;   // E*8 = 12.8 MB fits in bufA's first NN rows

    const int nbN  = (NN + 255) / 256;          // 391
    const int nG   = nbuck * NBLK;              // 100096
    const int nbGh = (nG + 255) / 256;          // 391
    const int chnk = (E + NBLK - 1) / NBLK;     // 6250

    hipMemsetAsync(Psum, 0, (size_t)NG * HID * 4, stream);
    hipMemsetAsync(bufA + (size_t)NN * HID, 0, HID * 2, stream);  // dummy row
    hipMemsetAsync(bufB + (size_t)NN * HID, 0, HID * 2, stream);
    k_hist<<<NBLK, 1024, 0, stream>>>(dst, Gh, E, nbuck, chnk);
    k_scan1<<<nbGh, 256, 0, stream>>>(Gh, Gh, bsumG, nG);
    k_scan2<<<1, 1024, 0, stream>>>(bsumG, nbGh);
    k_scan3g<<<nbGh, 256, 0, stream>>>(Gh, bsumG, bstart, nG, nbuck, E);
    k_partB <<<NBLK, 1024, 0, stream>>>(src, dst, Gh, packed, E, nbuck, chnk);
    k_placeC<<<nbuck, 512, 0, stream>>>(packed, bstart, rowptr, rend, dinv, meta, NN, nbuck);

    const int nbG = (NN + 63) / 64;             // 1563 (64 rows per block)
    const int nbA = ((size_t)NN * 64 + 255) / 256;

    // layer 1: G1 = dinv*(x@W1) ; H1 = relu(dinv*(G1[v]+sum G1[src]) + b1)
    k_gemm<IN_CH, false><<<nbG, 256, 0, stream>>>(x, W1, dinv, bufA, NN);
    k_agg<<<nbA, 256, 0, stream>>>(bufA, meta, rowptr, rend, dinv, b1, bufB, NN, 1, 0);
    // layer 2
    k_gemm<HID, true><<<nbG, 256, 0, stream>>>(bufB, W2, dinv, bufA, NN);
    k_agg<<<nbA, 256, 0, stream>>>(bufA, meta, rowptr, rend, dinv, b2, bufB, NN, 1, 1);
    // layer 3 (reordered) + pool + head
    k_agg<<<nbA, 256, 0, stream>>>(bufB, meta, rowptr, rend, dinv, nullptr, bufA, NN, 0, 0);
    k_pool<<<nbN, 256, 0, stream>>>(bufA, batch, Psum, NN);
    k_final<<<1, 640, 0, stream>>>(Psum, batch, NN, W3, b3, out, NG);
}

// Round 12
// 304.493 us; speedup vs baseline: 2.6547x; 1.0894x over previous
//
#include <hip/hip_runtime.h>
#include <math.h>

#define IN_CH 128
#define HID   64
#define NC    10
#define BSH   8       // 256 nodes per bucket
#define NBLK  256     // partition blocks
#define BPAD  772     // per-bucket meta slack: 3*256 pads + 4 align

typedef unsigned short bfu;
typedef __attribute__((ext_vector_type(8))) short bf16x8;
typedef __attribute__((ext_vector_type(4))) float f32x4;
typedef __attribute__((ext_vector_type(2))) float f32x2;

static __device__ __forceinline__ bfu bf16_of(float f) {
    unsigned u = __float_as_uint(f);
    unsigned r = (u + 0x7FFF + ((u >> 16) & 1)) >> 16;   // RNE
    return (bfu)r;
}
static __device__ __forceinline__ float f_of_bf16(bfu u) {
    return __uint_as_float(((unsigned)u) << 16);
}

// ---- fp8 e4m3 pack/unpack: HW cvt on gfx950 (imm word-select via template),
// software fallback otherwise ---------------------------------------------
#if __has_builtin(__builtin_amdgcn_cvt_pk_f32_fp8) && __has_builtin(__builtin_amdgcn_cvt_pk_fp8_f32)
template <bool HI>
static __device__ __forceinline__ f32x2 fp8_unpk(unsigned d) {
    return __builtin_amdgcn_cvt_pk_f32_fp8((int)d, HI);
}
template <bool HI>
static __device__ __forceinline__ int fp8_pk(float a, float b, int old) {
    return __builtin_amdgcn_cvt_pk_fp8_f32(a, b, old, HI);
}
#else
static __device__ __forceinline__ float fp8_dec1(unsigned b) {
    unsigned s = b >> 7, e = (b >> 3) & 15, m = b & 7;
    float v = (e == 0) ? ldexpf((float)m, -9) : ldexpf((float)(8 + m), (int)e - 10);
    return s ? -v : v;
}
static __device__ __forceinline__ unsigned fp8_enc1(float f) {
    unsigned u = __float_as_uint(f);
    unsigned s = (u >> 31) << 7;
    f = fabsf(f);
    if (!(f < 448.f)) return s | 0x7E;
    if (f < 0.015625f) {                   // subnormal range (< 2^-6)
        int q = (int)rintf(f * 512.f);
        return s | (unsigned)q;
    }
    int e; float fr = frexpf(f, &e);
    int q = (int)rintf(fr * 16.f);
    if (q == 16) { q = 8; e++; }
    int E = e + 6;
    if (E >= 16) return s | 0x7E;
    return s | (unsigned)((E << 3) | (q - 8));
}
template <bool HI>
static __device__ __forceinline__ f32x2 fp8_unpk(unsigned d) {
    unsigned w = HI ? (d >> 16) : d;
    f32x2 r; r.x = fp8_dec1(w & 0xFF); r.y = fp8_dec1((w >> 8) & 0xFF);
    return r;
}
template <bool HI>
static __device__ __forceinline__ int fp8_pk(float a, float b, int old) {
    unsigned p = fp8_enc1(a) | (fp8_enc1(b) << 8);
    return HI ? (int)(((unsigned)old & 0x0000FFFFu) | (p << 16))
              : (int)(((unsigned)old & 0xFFFF0000u) | p);
}
#endif

__device__ __forceinline__ int lower_bound_i(const int* a, int n, int v) {
    int lo = 0, hi = n;
    while (lo < hi) { int mid = (lo + hi) >> 1; if (a[mid] < v) lo = mid + 1; else hi = mid; }
    return lo;
}

// ---- bucket histogram (LDS only — no global atomics) --------------------

__global__ __launch_bounds__(1024) void k_hist(const int* __restrict__ dst,
                                               int* __restrict__ Gh,
                                               int E, int nbuck, int chunk) {
    __shared__ int h[512];
    for (int b = threadIdx.x; b < nbuck; b += blockDim.x) h[b] = 0;
    __syncthreads();
    int base = blockIdx.x * chunk;
    int lim  = min(base + chunk, E);
    for (int e = base + threadIdx.x; e < lim; e += blockDim.x)
        atomicAdd(&h[dst[e] >> BSH], 1);
    __syncthreads();
    for (int b = threadIdx.x; b < nbuck; b += blockDim.x)
        Gh[b * NBLK + blockIdx.x] = h[b];
}

// ---- hierarchical exclusive scan pieces ---------------------------------

__global__ void k_scan1(const int* __restrict__ cnt, int* __restrict__ excl,
                        int* __restrict__ bsum, int n) {
    __shared__ int s[256];
    int i = blockIdx.x * 256 + threadIdx.x;
    int v = (i < n) ? cnt[i] : 0;
    s[threadIdx.x] = v;
    __syncthreads();
    for (int off = 1; off < 256; off <<= 1) {
        int t = (threadIdx.x >= off) ? s[threadIdx.x - off] : 0;
        __syncthreads();
        s[threadIdx.x] += t;
        __syncthreads();
    }
    if (i < n) excl[i] = s[threadIdx.x] - v;
    if (threadIdx.x == 255) bsum[blockIdx.x] = s[255];
}

// single-block scan; also zeroes Psum + the two fp8 dummy rows (folded memsets)
__global__ void k_scan2(int* __restrict__ bsum, int nb, float* __restrict__ Psum,
                        unsigned* __restrict__ dumA, unsigned* __restrict__ dumB) {
    if (threadIdx.x < 16) { dumA[threadIdx.x] = 0u; dumB[threadIdx.x] = 0u; }
    for (int i = threadIdx.x; i < 64 * 64; i += 1024) Psum[i] = 0.f;
    __shared__ int s[1024];
    int v = (threadIdx.x < nb) ? bsum[threadIdx.x] : 0;
    s[threadIdx.x] = v;
    __syncthreads();
    for (int off = 1; off < 1024; off <<= 1) {
        int t = (threadIdx.x >= off) ? s[threadIdx.x - off] : 0;
        __syncthreads();
        s[threadIdx.x] += t;
        __syncthreads();
    }
    if (threadIdx.x < nb) bsum[threadIdx.x] = s[threadIdx.x] - v;
}

// add block offsets to Gh and extract bucket starts
__global__ void k_scan3g(int* __restrict__ Gh, const int* __restrict__ bsum,
                         int* __restrict__ bstart, int n, int nbuck, int E) {
    int i = blockIdx.x * 256 + threadIdx.x;
    if (i < n) {
        int v = Gh[i] + bsum[i >> 8];
        Gh[i] = v;
        if ((i & (NBLK - 1)) == 0) bstart[i / NBLK] = v;
    }
    if (i == 0) bstart[nbuck] = E;
}

// ---- partB: scatter (src,dst) into bucket-grouped order -----------------

__global__ __launch_bounds__(1024) void k_partB(const int* __restrict__ src,
                                                const int* __restrict__ dst,
                                                const int* __restrict__ Gh,
                                                int2* __restrict__ packed,
                                                int E, int nbuck, int chunk) {
    __shared__ int cur[512];
    for (int b = threadIdx.x; b < nbuck; b += blockDim.x)
        cur[b] = Gh[b * NBLK + blockIdx.x];
    __syncthreads();
    int base = blockIdx.x * chunk;
    int lim  = min(base + chunk, E);
    for (int e = base + threadIdx.x; e < lim; e += blockDim.x) {
        int d = dst[e], s = src[e];
        int pos = atomicAdd(&cur[d >> BSH], 1);
        packed[pos] = make_int2(s, d);
    }
}

// ---- placeC: per bucket — histogram -> PADDED rowptr/rend + dinv + meta -

__global__ __launch_bounds__(512) void k_placeC(const int2* __restrict__ packed,
                                                const int* __restrict__ bstart,
                                                int* __restrict__ rowptr,
                                                int* __restrict__ rend,
                                                float* __restrict__ dinv,
                                                int* __restrict__ meta,
                                                int nn, int nbuck) {
    __shared__ int hist[256];
    __shared__ int scn[256];
    __shared__ int cur[256];
    int tid = threadIdx.x;
    int b   = blockIdx.x;
    int nb0 = b << BSH;
    int nnb = min(1 << BSH, nn - nb0);
    if (tid < 256) hist[tid] = 0;
    __syncthreads();
    int lo = bstart[b], hi = bstart[b + 1];
    for (int e = lo + tid; e < hi; e += blockDim.x)
        atomicAdd(&hist[packed[e].y - nb0], 1);
    __syncthreads();
    int pd = 0;
    if (tid < 256) { pd = (hist[tid] + 3) & ~3; scn[tid] = pd; }
    __syncthreads();
    for (int off = 1; off < 256; off <<= 1) {
        int t = 0;
        if (tid < 256 && tid >= off) t = scn[tid - off];
        __syncthreads();
        if (tid < 256) scn[tid] += t;
        __syncthreads();
    }
    int meta0 = ((lo + 3) & ~3) + BPAD * b;   // aligned bucket meta start
    if (tid < nnb) {
        int rp = meta0 + scn[tid] - pd;
        rowptr[nb0 + tid] = rp;
        rend[nb0 + tid]   = rp + pd;
        cur[tid] = rp;
        dinv[nb0 + tid] = rsqrtf((float)(hist[tid] + 1));  // +1 self loop
        for (int k = hist[tid]; k < pd; k++) meta[rp + k] = nn;  // pads
    }
    __syncthreads();
    for (int e = lo + tid; e < hi; e += blockDim.x) {
        int2 p = packed[e];
        int pos = atomicAdd(&cur[p.y - nb0], 1);
        meta[pos] = p.x;
    }
}

// ---- Dense X@W via MFMA bf16 + dinv-scaled fp8 epilogue -----------------

template <int K, bool IN_BF16>
__global__ __launch_bounds__(256) void k_gemm(const void* __restrict__ Xv,
                                              const float* __restrict__ W,
                                              const float* __restrict__ dinv,
                                              unsigned char* __restrict__ G8, int n) {
    constexpr int KS = K + 8;
    __shared__ bfu wt[64 * KS];
    int tid = threadIdx.x;
    for (int i = tid; i < K * 64; i += 256) {     // stage W^T as bf16 (RNE)
        int k = i >> 6, nn2 = i & 63;
        wt[nn2 * KS + k] = bf16_of(W[i]);
    }
    __syncthreads();
    int wave = tid >> 6, lane = tid & 63;
    int m = lane & 15, q = lane >> 4;
    int row0 = blockIdx.x * 64 + wave * 16;
    int rowA = min(row0 + m, n - 1);              // clamp: OOB rows never stored
    f32x4 acc[4] = {{0.f,0.f,0.f,0.f},{0.f,0.f,0.f,0.f},
                    {0.f,0.f,0.f,0.f},{0.f,0.f,0.f,0.f}};
#pragma unroll
    for (int ks = 0; ks < K / 32; ks++) {
        bf16x8 a;
        if (IN_BF16) {
            a = *(const bf16x8*)((const bfu*)Xv + (size_t)rowA * 64 + ks * 32 + q * 8);
        } else {
            const float* xp = (const float*)Xv + (size_t)rowA * K + ks * 32 + q * 8;
            float4 v0 = *(const float4*)xp;
            float4 v1 = *(const float4*)(xp + 4);
            union { unsigned u[4]; bf16x8 v; } cvt;
            cvt.u[0] = __builtin_amdgcn_perm(__float_as_uint(v0.y), __float_as_uint(v0.x), 0x07060302u);
            cvt.u[1] = __builtin_amdgcn_perm(__float_as_uint(v0.w), __float_as_uint(v0.z), 0x07060302u);
            cvt.u[2] = __builtin_amdgcn_perm(__float_as_uint(v1.y), __float_as_uint(v1.x), 0x07060302u);
            cvt.u[3] = __builtin_amdgcn_perm(__float_as_uint(v1.w), __float_as_uint(v1.z), 0x07060302u);
            a = cvt.v;
        }
#pragma unroll
        for (int nt = 0; nt < 4; nt++) {
            bf16x8 b = *(const bf16x8*)&wt[(nt * 16 + m) * KS + ks * 32 + q * 8];
            acc[nt] = __builtin_amdgcn_mfma_f32_16x16x32_bf16(a, b, acc[nt], 0, 0, 0);
        }
    }
#pragma unroll
    for (int r = 0; r < 4; r++) {
        int grow = row0 + q * 4 + r;
        if (grow < n) {
            float dv = dinv[grow];
            int p01 = fp8_pk<false>(acc[0][r] * dv, acc[1][r] * dv, 0);
            int p23 = fp8_pk<false>(acc[2][r] * dv, acc[3][r] * dv, 0);
            unsigned char* gp = G8 + (size_t)grow * 64 + m;
            gp[0]  = (unsigned char)(p01 & 0xFF);
            gp[16] = (unsigned char)((p01 >> 8) & 0xFF);
            gp[32] = (unsigned char)(p23 & 0xFF);
            gp[48] = (unsigned char)((p23 >> 8) & 0xFF);
        }
    }
}

// ---- CSR gather agg: wave/node, 16 lanes x 4 cols, fp8 rows (64 B) ------
// Padded meta (multiple of 4, dummy=zero-row) -> maskless inner loop.

template <bool OUT_FP8>
__global__ void k_agg(const unsigned* __restrict__ G4, const int* __restrict__ meta,
                      const int* __restrict__ rowptr, const int* __restrict__ rend,
                      const float* __restrict__ dinv, const float* __restrict__ bias,
                      void* __restrict__ outv, int n, int do_relu, int post_scale) {
    int wid  = (blockIdx.x * blockDim.x + threadIdx.x) >> 6;
    int lane = threadIdx.x & 63;
    if (wid >= n) return;
    int col4 = lane & 15, equad = lane >> 4;
    int beg = rowptr[wid], pend = rend[wid];
    f32x2 aA = {0.f, 0.f}, aB = {0.f, 0.f};
    for (int e = beg + 4 * equad; e < pend; e += 16) {
        int4 m = *(const int4*)&meta[e];
        unsigned d0 = G4[(size_t)m.x * 16 + col4];
        unsigned d1 = G4[(size_t)m.y * 16 + col4];
        unsigned d2 = G4[(size_t)m.z * 16 + col4];
        unsigned d3 = G4[(size_t)m.w * 16 + col4];
        aA += fp8_unpk<false>(d0); aB += fp8_unpk<true>(d0);
        aA += fp8_unpk<false>(d1); aB += fp8_unpk<true>(d1);
        aA += fp8_unpk<false>(d2); aB += fp8_unpk<true>(d2);
        aA += fp8_unpk<false>(d3); aB += fp8_unpk<true>(d3);
    }
    float a0 = aA.x, a1 = aA.y, a2 = aB.x, a3 = aB.y;
    a0 += __shfl_down(a0, 32, 64); a1 += __shfl_down(a1, 32, 64);
    a2 += __shfl_down(a2, 32, 64); a3 += __shfl_down(a3, 32, 64);
    a0 += __shfl_down(a0, 16, 64); a1 += __shfl_down(a1, 16, 64);
    a2 += __shfl_down(a2, 16, 64); a3 += __shfl_down(a3, 16, 64);
    if (equad == 0) {
        unsigned sv = G4[(size_t)wid * 16 + col4];   // self loop (pre-scaled)
        f32x2 sl = fp8_unpk<false>(sv), sh = fp8_unpk<true>(sv);
        a0 += sl.x; a1 += sl.y; a2 += sh.x; a3 += sh.y;
        float dv = dinv[wid];
        a0 *= dv; a1 *= dv; a2 *= dv; a3 *= dv;
        if (bias) {
            float4 bv = *(const float4*)&bias[col4 * 4];
            a0 += bv.x; a1 += bv.y; a2 += bv.z; a3 += bv.w;
        }
        if (do_relu) {
            a0 = fmaxf(a0, 0.f); a1 = fmaxf(a1, 0.f);
            a2 = fmaxf(a2, 0.f); a3 = fmaxf(a3, 0.f);
        }
        if (post_scale) { a0 *= dv; a1 *= dv; a2 *= dv; a3 *= dv; }
        if (OUT_FP8) {
            int p = fp8_pk<false>(a0, a1, 0);
            p = fp8_pk<true>(a2, a3, p);
            ((unsigned*)outv)[(size_t)wid * 16 + col4] = (unsigned)p;
        } else {
            uint2 o;
            o.x = (unsigned)bf16_of(a0) | ((unsigned)bf16_of(a1) << 16);
            o.y = (unsigned)bf16_of(a2) | ((unsigned)bf16_of(a3) << 16);
            ((uint2*)outv)[(size_t)wid * 16 + col4] = o;
        }
    }
}

// ---- Mean pool, chunk-parallel (bf16 input, fp32 accum) -----------------

__global__ void k_pool(const bfu* __restrict__ G, const int* __restrict__ batch,
                       float* __restrict__ Psum, int n) {
    int base = blockIdx.x * 256;
    int lane = threadIdx.x & 63, rg = threadIdx.x >> 6;
    int lim = min(base + 256, n);
    int cur = -1;
    float acc = 0.f;
    for (int r = base + rg; r < lim; r += 4) {
        int g = batch[r];
        if (g != cur) {
            if (cur >= 0) atomicAdd(&Psum[cur * 64 + lane], acc);
            cur = g;
            acc = 0.f;
        }
        acc += f_of_bf16(G[(size_t)r * 64 + lane]);
    }
    if (cur >= 0) atomicAdd(&Psum[cur * 64 + lane], acc);
}

// ---- mean + pooled@W3 + b3 + log_softmax --------------------------------

__global__ void k_final(const float* __restrict__ Psum, const int* __restrict__ batch,
                        int n, const float* __restrict__ W3, const float* __restrict__ b3,
                        float* __restrict__ out, int ng) {
    __shared__ float P[64 * 64];
    __shared__ float s[64][NC];
    __shared__ float lse[64];
    __shared__ float invc[64];
    int t = threadIdx.x;
    if (t < ng) {
        int lo = lower_bound_i(batch, n, t);
        int hi = lower_bound_i(batch, n, t + 1);
        invc[t] = 1.f / (float)max(hi - lo, 1);
    }
    __syncthreads();
    for (int i = t; i < ng * 64; i += blockDim.x) P[i] = Psum[i] * invc[i >> 6];
    __syncthreads();
    if (t < ng * NC) {
        int g = t / NC, c = t % NC;
        float acc = b3[c];
        for (int k = 0; k < 64; k++) acc += P[g * 64 + k] * W3[k * NC + c];
        s[g][c] = acc;
    }
    __syncthreads();
    if (t < ng) {
        float m = -1e30f;
        for (int c = 0; c < NC; c++) m = fmaxf(m, s[t][c]);
        float sum = 0.f;
        for (int c = 0; c < NC; c++) sum += expf(s[t][c] - m);
        lse[t] = m + logf(sum);
    }
    __syncthreads();
    if (t < ng * NC) {
        int g = t / NC, c = t % NC;
        out[t] = s[g][c] - lse[g];
    }
}

// ---- launch -------------------------------------------------------------

extern "C" void kernel_launch(void* const* d_in, const int* in_sizes, int n_in,
                              void* d_out, int out_size, void* d_ws, size_t ws_size,
                              hipStream_t stream) {
    const float* x     = (const float*)d_in[0];
    const int*   ei    = (const int*)  d_in[1];
    const int*   batch = (const int*)  d_in[2];
    const float* W1    = (const float*)d_in[3];
    const float* b1    = (const float*)d_in[4];
    const float* W2    = (const float*)d_in[5];
    const float* b2    = (const float*)d_in[6];
    const float* W3    = (const float*)d_in[7];
    const float* b3    = (const float*)d_in[8];
    float*       out   = (float*)d_out;

    const int NN = in_sizes[0] / IN_CH;   // 100000
    const int E  = in_sizes[1] / 2;       // 1600000
    const int NG = out_size / NC;         // 64
    const int nbuck = (NN + (1 << BSH) - 1) >> BSH;  // 391

    const int* src = ei;
    const int* dst = ei + E;

    char* ws = (char*)d_ws;
    size_t off = 0;
    auto carve = [&](size_t bytes) -> char* {
        char* p = ws + off;
        off = (off + bytes + 255) & ~(size_t)255;
        return p;
    };
    int*   rowptr = (int*)  carve((size_t)NN * 4);
    int*   rend   = (int*)  carve((size_t)NN * 4);
    float* dinv   = (float*)carve((size_t)NN * 4);
    int*   bsumG  = (int*)  carve(4096);
    int*   bstart = (int*)  carve((size_t)(nbuck + 1) * 4);
    int*   Gh     = (int*)  carve((size_t)nbuck * NBLK * 4);
    int*   meta   = (int*)  carve(((size_t)E + (size_t)BPAD * nbuck + 64) * 4);
    unsigned char* f8A = (unsigned char*)carve((size_t)(NN + 1) * 64);  // G1 then G3
    unsigned char* f8B = (unsigned char*)carve((size_t)(NN + 1) * 64);  // G2
    bfu*   hbuf   = (bfu*)  carve((size_t)NN * HID * 2);  // H1, then agg3 out
    float* Psum   = (float*)carve((size_t)NG * HID * 4);
    (void)ws_size;

    int2* packed = (int2*)hbuf;   // E*8 = 12.8 MB == hbuf size (dead until agg1)

    const int nbN  = (NN + 255) / 256;          // 391
    const int nG   = nbuck * NBLK;              // 100096
    const int nbGh = (nG + 255) / 256;          // 391
    const int chnk = (E + NBLK - 1) / NBLK;     // 6250

    k_hist<<<NBLK, 1024, 0, stream>>>(dst, Gh, E, nbuck, chnk);
    k_scan1<<<nbGh, 256, 0, stream>>>(Gh, Gh, bsumG, nG);
    k_scan2<<<1, 1024, 0, stream>>>(bsumG, nbGh, Psum,
                                    (unsigned*)(f8A + (size_t)NN * 64),
                                    (unsigned*)(f8B + (size_t)NN * 64));
    k_scan3g<<<nbGh, 256, 0, stream>>>(Gh, bsumG, bstart, nG, nbuck, E);
    k_partB <<<NBLK, 1024, 0, stream>>>(src, dst, Gh, packed, E, nbuck, chnk);
    k_placeC<<<nbuck, 512, 0, stream>>>(packed, bstart, rowptr, rend, dinv, meta, NN, nbuck);

    const int nbG = (NN + 63) / 64;             // 1563 (64 rows per block)
    const int nbA = ((size_t)NN * 64 + 255) / 256;

    // layer 1: G1 = fp8(dinv*(x@W1)) ; H1 = bf16(relu(dinv*(G1[v]+sum)+b1))
    k_gemm<IN_CH, false><<<nbG, 256, 0, stream>>>(x, W1, dinv, f8A, NN);
    k_agg<false><<<nbA, 256, 0, stream>>>((const unsigned*)f8A, meta, rowptr, rend,
                                          dinv, b1, hbuf, NN, 1, 0);
    // layer 2: G2 = fp8(dinv*(H1@W2)) ; G3 = fp8(dinv*relu(dinv*(...)+b2))
    k_gemm<HID, true><<<nbG, 256, 0, stream>>>(hbuf, W2, dinv, f8B, NN);
    k_agg<true><<<nbA, 256, 0, stream>>>((const unsigned*)f8B, meta, rowptr, rend,
                                         dinv, b2, f8A, NN, 1, 1);
    // layer 3 (reordered): p = dinv*(G3[v]+sum G3[src]) -> bf16 ; pool ; head
    k_agg<false><<<nbA, 256, 0, stream>>>((const unsigned*)f8A, meta, rowptr, rend,
                                          dinv, nullptr, hbuf, NN, 0, 0);
    k_pool<<<nbN, 256, 0, stream>>>(hbuf, batch, Psum, NN);
    k_final<<<1, 640, 0, stream>>>(Psum, batch, NN, W3, b3, out, NG);
}

// Round 13
// 303.899 us; speedup vs baseline: 2.6599x; 1.0020x over previous
//
#include <hip/hip_runtime.h>
#include <math.h>

#define IN_CH 128
#define HID   64
#define NC    10
#define BSH   8       // 256 nodes per bucket
#define NBLK  256     // partition blocks
#define BPAD  772     // per-bucket meta slack: 3*256 pads + 4 align

typedef unsigned short bfu;
typedef __attribute__((ext_vector_type(8))) short bf16x8;
typedef __attribute__((ext_vector_type(4))) float f32x4;
typedef __attribute__((ext_vector_type(2))) float f32x2;

static __device__ __forceinline__ bfu bf16_of(float f) {
    unsigned u = __float_as_uint(f);
    unsigned r = (u + 0x7FFF + ((u >> 16) & 1)) >> 16;   // RNE
    return (bfu)r;
}
static __device__ __forceinline__ float f_of_bf16(bfu u) {
    return __uint_as_float(((unsigned)u) << 16);
}

// ---- fp8 e4m3 pack/unpack: HW cvt on gfx950 (imm word-select via template),
// software fallback otherwise ---------------------------------------------
#if __has_builtin(__builtin_amdgcn_cvt_pk_f32_fp8) && __has_builtin(__builtin_amdgcn_cvt_pk_fp8_f32)
template <bool HI>
static __device__ __forceinline__ f32x2 fp8_unpk(unsigned d) {
    return __builtin_amdgcn_cvt_pk_f32_fp8((int)d, HI);
}
template <bool HI>
static __device__ __forceinline__ int fp8_pk(float a, float b, int old) {
    return __builtin_amdgcn_cvt_pk_fp8_f32(a, b, old, HI);
}
#else
static __device__ __forceinline__ float fp8_dec1(unsigned b) {
    unsigned s = b >> 7, e = (b >> 3) & 15, m = b & 7;
    float v = (e == 0) ? ldexpf((float)m, -9) : ldexpf((float)(8 + m), (int)e - 10);
    return s ? -v : v;
}
static __device__ __forceinline__ unsigned fp8_enc1(float f) {
    unsigned u = __float_as_uint(f);
    unsigned s = (u >> 31) << 7;
    f = fabsf(f);
    if (!(f < 448.f)) return s | 0x7E;
    if (f < 0.015625f) {                   // subnormal range (< 2^-6)
        int q = (int)rintf(f * 512.f);
        return s | (unsigned)q;
    }
    int e; float fr = frexpf(f, &e);
    int q = (int)rintf(fr * 16.f);
    if (q == 16) { q = 8; e++; }
    int E = e + 6;
    if (E >= 16) return s | 0x7E;
    return s | (unsigned)((E << 3) | (q - 8));
}
template <bool HI>
static __device__ __forceinline__ f32x2 fp8_unpk(unsigned d) {
    unsigned w = HI ? (d >> 16) : d;
    f32x2 r; r.x = fp8_dec1(w & 0xFF); r.y = fp8_dec1((w >> 8) & 0xFF);
    return r;
}
template <bool HI>
static __device__ __forceinline__ int fp8_pk(float a, float b, int old) {
    unsigned p = fp8_enc1(a) | (fp8_enc1(b) << 8);
    return HI ? (int)(((unsigned)old & 0x0000FFFFu) | (p << 16))
              : (int)(((unsigned)old & 0xFFFF0000u) | p);
}
#endif

__device__ __forceinline__ int lower_bound_i(const int* a, int n, int v) {
    int lo = 0, hi = n;
    while (lo < hi) { int mid = (lo + hi) >> 1; if (a[mid] < v) lo = mid + 1; else hi = mid; }
    return lo;
}

// ---- bucket histogram (LDS only — no global atomics) --------------------

__global__ __launch_bounds__(1024) void k_hist(const int* __restrict__ dst,
                                               int* __restrict__ Gh,
                                               int E, int nbuck, int chunk) {
    __shared__ int h[512];
    for (int b = threadIdx.x; b < nbuck; b += blockDim.x) h[b] = 0;
    __syncthreads();
    int base = blockIdx.x * chunk;
    int lim  = min(base + chunk, E);
    for (int e = base + threadIdx.x; e < lim; e += blockDim.x)
        atomicAdd(&h[dst[e] >> BSH], 1);
    __syncthreads();
    for (int b = threadIdx.x; b < nbuck; b += blockDim.x)
        Gh[b * NBLK + blockIdx.x] = h[b];
}

// ---- hierarchical exclusive scan pieces ---------------------------------
// NOTE: full scanned value of Gh[i] is Gh[i] + bsumG[i>>8]; consumers add
// bsumG inline (k_scan3g pass deleted).

__global__ void k_scan1(const int* __restrict__ cnt, int* __restrict__ excl,
                        int* __restrict__ bsum, int n) {
    __shared__ int s[256];
    int i = blockIdx.x * 256 + threadIdx.x;
    int v = (i < n) ? cnt[i] : 0;
    s[threadIdx.x] = v;
    __syncthreads();
    for (int off = 1; off < 256; off <<= 1) {
        int t = (threadIdx.x >= off) ? s[threadIdx.x - off] : 0;
        __syncthreads();
        s[threadIdx.x] += t;
        __syncthreads();
    }
    if (i < n) excl[i] = s[threadIdx.x] - v;
    if (threadIdx.x == 255) bsum[blockIdx.x] = s[255];
}

// single-block scan; also zeroes Psum + the two fp8 dummy rows (folded memsets)
__global__ void k_scan2(int* __restrict__ bsum, int nb, float* __restrict__ Psum,
                        unsigned* __restrict__ dumA, unsigned* __restrict__ dumB) {
    if (threadIdx.x < 16) { dumA[threadIdx.x] = 0u; dumB[threadIdx.x] = 0u; }
    for (int i = threadIdx.x; i < 64 * 64; i += 1024) Psum[i] = 0.f;
    __shared__ int s[1024];
    int v = (threadIdx.x < nb) ? bsum[threadIdx.x] : 0;
    s[threadIdx.x] = v;
    __syncthreads();
    for (int off = 1; off < 1024; off <<= 1) {
        int t = (threadIdx.x >= off) ? s[threadIdx.x - off] : 0;
        __syncthreads();
        s[threadIdx.x] += t;
        __syncthreads();
    }
    if (threadIdx.x < nb) bsum[threadIdx.x] = s[threadIdx.x] - v;
}

// ---- partB: scatter compressed (src<<8|dloc) into bucket-grouped order --
// scanned cursor = Gh[b*256+blk] + bsumG[b] (inline; scan3g deleted).

__global__ __launch_bounds__(1024) void k_partB(const int* __restrict__ src,
                                                const int* __restrict__ dst,
                                                const int* __restrict__ Gh,
                                                const int* __restrict__ bsumG,
                                                unsigned* __restrict__ packed,
                                                int E, int nbuck, int chunk) {
    __shared__ int cur[512];
    for (int b = threadIdx.x; b < nbuck; b += blockDim.x)
        cur[b] = Gh[b * NBLK + blockIdx.x] + bsumG[b];
    __syncthreads();
    int base = blockIdx.x * chunk;
    int lim  = min(base + chunk, E);
    for (int e = base + threadIdx.x; e < lim; e += blockDim.x) {
        int d = dst[e], s = src[e];
        int pos = atomicAdd(&cur[d >> BSH], 1);
        packed[pos] = ((unsigned)s << 8) | (unsigned)(d & 255);
    }
}

// ---- placeC: per bucket — histogram -> PADDED rowptr/rend + dinv + meta -

__global__ __launch_bounds__(512) void k_placeC(const unsigned* __restrict__ packed,
                                                const int* __restrict__ Gh,
                                                const int* __restrict__ bsumG,
                                                int* __restrict__ rowptr,
                                                int* __restrict__ rend,
                                                float* __restrict__ dinv,
                                                int* __restrict__ meta,
                                                int nn, int nbuck, int E) {
    __shared__ int hist[256];
    __shared__ int scn[256];
    __shared__ int cur[256];
    int tid = threadIdx.x;
    int b   = blockIdx.x;
    int nb0 = b << BSH;
    int nnb = min(1 << BSH, nn - nb0);
    if (tid < 256) hist[tid] = 0;
    __syncthreads();
    int lo = Gh[b * NBLK] + bsumG[b];
    int hi = (b + 1 < nbuck) ? (Gh[(b + 1) * NBLK] + bsumG[b + 1]) : E;
    for (int e = lo + tid; e < hi; e += blockDim.x)
        atomicAdd(&hist[packed[e] & 255u], 1);
    __syncthreads();
    int pd = 0;
    if (tid < 256) { pd = (hist[tid] + 3) & ~3; scn[tid] = pd; }
    __syncthreads();
    for (int off = 1; off < 256; off <<= 1) {
        int t = 0;
        if (tid < 256 && tid >= off) t = scn[tid - off];
        __syncthreads();
        if (tid < 256) scn[tid] += t;
        __syncthreads();
    }
    int meta0 = ((lo + 3) & ~3) + BPAD * b;   // aligned bucket meta start
    if (tid < nnb) {
        int rp = meta0 + scn[tid] - pd;
        rowptr[nb0 + tid] = rp;
        rend[nb0 + tid]   = rp + pd;
        cur[tid] = rp;
        dinv[nb0 + tid] = rsqrtf((float)(hist[tid] + 1));  // +1 self loop
        for (int k = hist[tid]; k < pd; k++) meta[rp + k] = nn;  // pads
    }
    __syncthreads();
    for (int e = lo + tid; e < hi; e += blockDim.x) {
        unsigned p = packed[e];
        int pos = atomicAdd(&cur[p & 255u], 1);
        meta[pos] = (int)(p >> 8);
    }
}

// ---- Dense X@W via MFMA bf16 + dinv-scaled fp8 epilogue -----------------

template <int K, bool IN_BF16>
__global__ __launch_bounds__(256) void k_gemm(const void* __restrict__ Xv,
                                              const float* __restrict__ W,
                                              const float* __restrict__ dinv,
                                              unsigned char* __restrict__ G8, int n) {
    constexpr int KS = K + 8;
    __shared__ bfu wt[64 * KS];
    int tid = threadIdx.x;
    for (int i = tid; i < K * 64; i += 256) {     // stage W^T as bf16 (RNE)
        int k = i >> 6, nn2 = i & 63;
        wt[nn2 * KS + k] = bf16_of(W[i]);
    }
    __syncthreads();
    int wave = tid >> 6, lane = tid & 63;
    int m = lane & 15, q = lane >> 4;
    int row0 = blockIdx.x * 64 + wave * 16;
    int rowA = min(row0 + m, n - 1);              // clamp: OOB rows never stored
    f32x4 acc[4] = {{0.f,0.f,0.f,0.f},{0.f,0.f,0.f,0.f},
                    {0.f,0.f,0.f,0.f},{0.f,0.f,0.f,0.f}};
#pragma unroll
    for (int ks = 0; ks < K / 32; ks++) {
        bf16x8 a;
        if (IN_BF16) {
            a = *(const bf16x8*)((const bfu*)Xv + (size_t)rowA * 64 + ks * 32 + q * 8);
        } else {
            const float* xp = (const float*)Xv + (size_t)rowA * K + ks * 32 + q * 8;
            float4 v0 = *(const float4*)xp;
            float4 v1 = *(const float4*)(xp + 4);
            union { unsigned u[4]; bf16x8 v; } cvt;
            cvt.u[0] = __builtin_amdgcn_perm(__float_as_uint(v0.y), __float_as_uint(v0.x), 0x07060302u);
            cvt.u[1] = __builtin_amdgcn_perm(__float_as_uint(v0.w), __float_as_uint(v0.z), 0x07060302u);
            cvt.u[2] = __builtin_amdgcn_perm(__float_as_uint(v1.y), __float_as_uint(v1.x), 0x07060302u);
            cvt.u[3] = __builtin_amdgcn_perm(__float_as_uint(v1.w), __float_as_uint(v1.z), 0x07060302u);
            a = cvt.v;
        }
#pragma unroll
        for (int nt = 0; nt < 4; nt++) {
            bf16x8 b = *(const bf16x8*)&wt[(nt * 16 + m) * KS + ks * 32 + q * 8];
            acc[nt] = __builtin_amdgcn_mfma_f32_16x16x32_bf16(a, b, acc[nt], 0, 0, 0);
        }
    }
#pragma unroll
    for (int r = 0; r < 4; r++) {
        int grow = row0 + q * 4 + r;
        if (grow < n) {
            float dv = dinv[grow];
            int p01 = fp8_pk<false>(acc[0][r] * dv, acc[1][r] * dv, 0);
            int p23 = fp8_pk<false>(acc[2][r] * dv, acc[3][r] * dv, 0);
            unsigned char* gp = G8 + (size_t)grow * 64 + m;
            gp[0]  = (unsigned char)(p01 & 0xFF);
            gp[16] = (unsigned char)((p01 >> 8) & 0xFF);
            gp[32] = (unsigned char)(p23 & 0xFF);
            gp[48] = (unsigned char)((p23 >> 8) & 0xFF);
        }
    }
}

// ---- CSR gather agg: wave/node, 16 lanes x 4 cols, fp8 rows (64 B) ------
// Padded meta (multiple of 4, dummy=zero-row) -> maskless inner loop.

template <bool OUT_FP8>
__global__ void k_agg(const unsigned* __restrict__ G4, const int* __restrict__ meta,
                      const int* __restrict__ rowptr, const int* __restrict__ rend,
                      const float* __restrict__ dinv, const float* __restrict__ bias,
                      void* __restrict__ outv, int n, int do_relu, int post_scale) {
    int wid  = (blockIdx.x * blockDim.x + threadIdx.x) >> 6;
    int lane = threadIdx.x & 63;
    if (wid >= n) return;
    int col4 = lane & 15, equad = lane >> 4;
    int beg = rowptr[wid], pend = rend[wid];
    f32x2 aA = {0.f, 0.f}, aB = {0.f, 0.f};
    for (int e = beg + 4 * equad; e < pend; e += 16) {
        int4 m = *(const int4*)&meta[e];
        unsigned d0 = G4[(size_t)m.x * 16 + col4];
        unsigned d1 = G4[(size_t)m.y * 16 + col4];
        unsigned d2 = G4[(size_t)m.z * 16 + col4];
        unsigned d3 = G4[(size_t)m.w * 16 + col4];
        aA += fp8_unpk<false>(d0); aB += fp8_unpk<true>(d0);
        aA += fp8_unpk<false>(d1); aB += fp8_unpk<true>(d1);
        aA += fp8_unpk<false>(d2); aB += fp8_unpk<true>(d2);
        aA += fp8_unpk<false>(d3); aB += fp8_unpk<true>(d3);
    }
    float a0 = aA.x, a1 = aA.y, a2 = aB.x, a3 = aB.y;
    a0 += __shfl_down(a0, 32, 64); a1 += __shfl_down(a1, 32, 64);
    a2 += __shfl_down(a2, 32, 64); a3 += __shfl_down(a3, 32, 64);
    a0 += __shfl_down(a0, 16, 64); a1 += __shfl_down(a1, 16, 64);
    a2 += __shfl_down(a2, 16, 64); a3 += __shfl_down(a3, 16, 64);
    if (equad == 0) {
        unsigned sv = G4[(size_t)wid * 16 + col4];   // self loop (pre-scaled)
        f32x2 sl = fp8_unpk<false>(sv), sh = fp8_unpk<true>(sv);
        a0 += sl.x; a1 += sl.y; a2 += sh.x; a3 += sh.y;
        float dv = dinv[wid];
        a0 *= dv; a1 *= dv; a2 *= dv; a3 *= dv;
        if (bias) {
            float4 bv = *(const float4*)&bias[col4 * 4];
            a0 += bv.x; a1 += bv.y; a2 += bv.z; a3 += bv.w;
        }
        if (do_relu) {
            a0 = fmaxf(a0, 0.f); a1 = fmaxf(a1, 0.f);
            a2 = fmaxf(a2, 0.f); a3 = fmaxf(a3, 0.f);
        }
        if (post_scale) { a0 *= dv; a1 *= dv; a2 *= dv; a3 *= dv; }
        if (OUT_FP8) {
            int p = fp8_pk<false>(a0, a1, 0);
            p = fp8_pk<true>(a2, a3, p);
            ((unsigned*)outv)[(size_t)wid * 16 + col4] = (unsigned)p;
        } else {
            uint2 o;
            o.x = (unsigned)bf16_of(a0) | ((unsigned)bf16_of(a1) << 16);
            o.y = (unsigned)bf16_of(a2) | ((unsigned)bf16_of(a3) << 16);
            ((uint2*)outv)[(size_t)wid * 16 + col4] = o;
        }
    }
}

// ---- Mean pool, chunk-parallel (bf16 input, fp32 accum) -----------------

__global__ void k_pool(const bfu* __restrict__ G, const int* __restrict__ batch,
                       float* __restrict__ Psum, int n) {
    int base = blockIdx.x * 256;
    int lane = threadIdx.x & 63, rg = threadIdx.x >> 6;
    int lim = min(base + 256, n);
    int cur = -1;
    float acc = 0.f;
    for (int r = base + rg; r < lim; r += 4) {
        int g = batch[r];
        if (g != cur) {
            if (cur >= 0) atomicAdd(&Psum[cur * 64 + lane], acc);
            cur = g;
            acc = 0.f;
        }
        acc += f_of_bf16(G[(size_t)r * 64 + lane]);
    }
    if (cur >= 0) atomicAdd(&Psum[cur * 64 + lane], acc);
}

// ---- mean + pooled@W3 + b3 + log_softmax --------------------------------

__global__ void k_final(const float* __restrict__ Psum, const int* __restrict__ batch,
                        int n, const float* __restrict__ W3, const float* __restrict__ b3,
                        float* __restrict__ out, int ng) {
    __shared__ float P[64 * 64];
    __shared__ float s[64][NC];
    __shared__ float lse[64];
    __shared__ float invc[64];
    int t = threadIdx.x;
    if (t < ng) {
        int lo = lower_bound_i(batch, n, t);
        int hi = lower_bound_i(batch, n, t + 1);
        invc[t] = 1.f / (float)max(hi - lo, 1);
    }
    __syncthreads();
    for (int i = t; i < ng * 64; i += blockDim.x) P[i] = Psum[i] * invc[i >> 6];
    __syncthreads();
    if (t < ng * NC) {
        int g = t / NC, c = t % NC;
        float acc = b3[c];
        for (int k = 0; k < 64; k++) acc += P[g * 64 + k] * W3[k * NC + c];
        s[g][c] = acc;
    }
    __syncthreads();
    if (t < ng) {
        float m = -1e30f;
        for (int c = 0; c < NC; c++) m = fmaxf(m, s[t][c]);
        float sum = 0.f;
        for (int c = 0; c < NC; c++) sum += expf(s[t][c] - m);
        lse[t] = m + logf(sum);
    }
    __syncthreads();
    if (t < ng * NC) {
        int g = t / NC, c = t % NC;
        out[t] = s[g][c] - lse[g];
    }
}

// ---- launch -------------------------------------------------------------

extern "C" void kernel_launch(void* const* d_in, const int* in_sizes, int n_in,
                              void* d_out, int out_size, void* d_ws, size_t ws_size,
                              hipStream_t stream) {
    const float* x     = (const float*)d_in[0];
    const int*   ei    = (const int*)  d_in[1];
    const int*   batch = (const int*)  d_in[2];
    const float* W1    = (const float*)d_in[3];
    const float* b1    = (const float*)d_in[4];
    const float* W2    = (const float*)d_in[5];
    const float* b2    = (const float*)d_in[6];
    const float* W3    = (const float*)d_in[7];
    const float* b3    = (const float*)d_in[8];
    float*       out   = (float*)d_out;

    const int NN = in_sizes[0] / IN_CH;   // 100000
    const int E  = in_sizes[1] / 2;       // 1600000
    const int NG = out_size / NC;         // 64
    const int nbuck = (NN + (1 << BSH) - 1) >> BSH;  // 391

    const int* src = ei;
    const int* dst = ei + E;

    char* ws = (char*)d_ws;
    size_t off = 0;
    auto carve = [&](size_t bytes) -> char* {
        char* p = ws + off;
        off = (off + bytes + 255) & ~(size_t)255;
        return p;
    };
    int*   rowptr = (int*)  carve((size_t)NN * 4);
    int*   rend   = (int*)  carve((size_t)NN * 4);
    float* dinv   = (float*)carve((size_t)NN * 4);
    int*   bsumG  = (int*)  carve(4096);
    int*   Gh     = (int*)  carve((size_t)nbuck * NBLK * 4);
    int*   meta   = (int*)  carve(((size_t)E + (size_t)BPAD * nbuck + 64) * 4);
    unsigned char* f8A = (unsigned char*)carve((size_t)(NN + 1) * 64);  // G1 then G3
    unsigned char* f8B = (unsigned char*)carve((size_t)(NN + 1) * 64);  // G2
    bfu*   hbuf   = (bfu*)  carve((size_t)NN * HID * 2);  // H1, then agg3 out
    float* Psum   = (float*)carve((size_t)NG * HID * 4);
    (void)ws_size;

    unsigned* packed = (unsigned*)hbuf;   // E*4 = 6.4 MB fits (dead until agg1)

    const int nbN  = (NN + 255) / 256;          // 391
    const int nG   = nbuck * NBLK;              // 100096
    const int nbGh = (nG + 255) / 256;          // 391
    const int chnk = (E + NBLK - 1) / NBLK;     // 6250

    k_hist<<<NBLK, 1024, 0, stream>>>(dst, Gh, E, nbuck, chnk);
    k_scan1<<<nbGh, 256, 0, stream>>>(Gh, Gh, bsumG, nG);
    k_scan2<<<1, 1024, 0, stream>>>(bsumG, nbGh, Psum,
                                    (unsigned*)(f8A + (size_t)NN * 64),
                                    (unsigned*)(f8B + (size_t)NN * 64));
    k_partB <<<NBLK, 1024, 0, stream>>>(src, dst, Gh, bsumG, packed, E, nbuck, chnk);
    k_placeC<<<nbuck, 512, 0, stream>>>(packed, Gh, bsumG, rowptr, rend, dinv,
                                        meta, NN, nbuck, E);

    const int nbG = (NN + 63) / 64;             // 1563 (64 rows per block)
    const int nbA = ((size_t)NN * 64 + 255) / 256;

    // layer 1: G1 = fp8(dinv*(x@W1)) ; H1 = bf16(relu(dinv*(G1[v]+sum)+b1))
    k_gemm<IN_CH, false><<<nbG, 256, 0, stream>>>(x, W1, dinv, f8A, NN);
    k_agg<false><<<nbA, 256, 0, stream>>>((const unsigned*)f8A, meta, rowptr, rend,
                                          dinv, b1, hbuf, NN, 1, 0);
    // layer 2: G2 = fp8(dinv*(H1@W2)) ; G3 = fp8(dinv*relu(dinv*(...)+b2))
    k_gemm<HID, true><<<nbG, 256, 0, stream>>>(hbuf, W2, dinv, f8B, NN);
    k_agg<true><<<nbA, 256, 0, stream>>>((const unsigned*)f8B, meta, rowptr, rend,
                                         dinv, b2, f8A, NN, 1, 1);
    // layer 3 (reordered): p = dinv*(G3[v]+sum G3[src]) -> bf16 ; pool ; head
    k_agg<false><<<nbA, 256, 0, stream>>>((const unsigned*)f8A, meta, rowptr, rend,
                                          dinv, nullptr, hbuf, NN, 0, 0);
    k_pool<<<nbN, 256, 0, stream>>>(hbuf, batch, Psum, NN);
    k_final<<<1, 640, 0, stream>>>(Psum, batch, NN, W3, b3, out, NG);
}

// Round 14
// 271.116 us; speedup vs baseline: 2.9815x; 1.1209x over previous
//
#include <hip/hip_runtime.h>
#include <math.h>

#define IN_CH 128
#define HID   64
#define NC    10
#define BSH   8       // 256 nodes per bucket
#define NBLK  256     // partition blocks
#define BPAD  772     // per-bucket meta slack: 3*256 pads + 4 align

typedef unsigned short bfu;
typedef __attribute__((ext_vector_type(8))) short bf16x8;
typedef __attribute__((ext_vector_type(4))) float f32x4;
typedef __attribute__((ext_vector_type(2))) float f32x2;

static __device__ __forceinline__ bfu bf16_of(float f) {
    unsigned u = __float_as_uint(f);
    unsigned r = (u + 0x7FFF + ((u >> 16) & 1)) >> 16;   // RNE
    return (bfu)r;
}
static __device__ __forceinline__ float f_of_bf16(bfu u) {
    return __uint_as_float(((unsigned)u) << 16);
}

// ---- fp8 e4m3 pack/unpack: HW cvt on gfx950 (imm word-select via template),
// software fallback otherwise ---------------------------------------------
#if __has_builtin(__builtin_amdgcn_cvt_pk_f32_fp8) && __has_builtin(__builtin_amdgcn_cvt_pk_fp8_f32)
template <bool HI>
static __device__ __forceinline__ f32x2 fp8_unpk(unsigned d) {
    return __builtin_amdgcn_cvt_pk_f32_fp8((int)d, HI);
}
template <bool HI>
static __device__ __forceinline__ int fp8_pk(float a, float b, int old) {
    return __builtin_amdgcn_cvt_pk_fp8_f32(a, b, old, HI);
}
#else
static __device__ __forceinline__ float fp8_dec1(unsigned b) {
    unsigned s = b >> 7, e = (b >> 3) & 15, m = b & 7;
    float v = (e == 0) ? ldexpf((float)m, -9) : ldexpf((float)(8 + m), (int)e - 10);
    return s ? -v : v;
}
static __device__ __forceinline__ unsigned fp8_enc1(float f) {
    unsigned u = __float_as_uint(f);
    unsigned s = (u >> 31) << 7;
    f = fabsf(f);
    if (!(f < 448.f)) return s | 0x7E;
    if (f < 0.015625f) {                   // subnormal range (< 2^-6)
        int q = (int)rintf(f * 512.f);
        return s | (unsigned)q;
    }
    int e; float fr = frexpf(f, &e);
    int q = (int)rintf(fr * 16.f);
    if (q == 16) { q = 8; e++; }
    int E = e + 6;
    if (E >= 16) return s | 0x7E;
    return s | (unsigned)((E << 3) | (q - 8));
}
template <bool HI>
static __device__ __forceinline__ f32x2 fp8_unpk(unsigned d) {
    unsigned w = HI ? (d >> 16) : d;
    f32x2 r; r.x = fp8_dec1(w & 0xFF); r.y = fp8_dec1((w >> 8) & 0xFF);
    return r;
}
template <bool HI>
static __device__ __forceinline__ int fp8_pk(float a, float b, int old) {
    unsigned p = fp8_enc1(a) | (fp8_enc1(b) << 8);
    return HI ? (int)(((unsigned)old & 0x0000FFFFu) | (p << 16))
              : (int)(((unsigned)old & 0xFFFF0000u) | p);
}
#endif

__device__ __forceinline__ int lower_bound_i(const int* a, int n, int v) {
    int lo = 0, hi = n;
    while (lo < hi) { int mid = (lo + hi) >> 1; if (a[mid] < v) lo = mid + 1; else hi = mid; }
    return lo;
}

// ---- bucket histogram (LDS only — no global atomics) --------------------

__global__ __launch_bounds__(1024) void k_hist(const int* __restrict__ dst,
                                               int* __restrict__ Gh,
                                               int E, int nbuck, int chunk) {
    __shared__ int h[512];
    for (int b = threadIdx.x; b < nbuck; b += blockDim.x) h[b] = 0;
    __syncthreads();
    int base = blockIdx.x * chunk;
    int lim  = min(base + chunk, E);
    for (int e = base + threadIdx.x; e < lim; e += blockDim.x)
        atomicAdd(&h[dst[e] >> BSH], 1);
    __syncthreads();
    for (int b = threadIdx.x; b < nbuck; b += blockDim.x)
        Gh[b * NBLK + blockIdx.x] = h[b];
}

// ---- hierarchical exclusive scan pieces ---------------------------------
// Full scanned value of Gh[i] is Gh[i] + bsumG[i>>8]; consumers add inline.

__global__ void k_scan1(const int* __restrict__ cnt, int* __restrict__ excl,
                        int* __restrict__ bsum, int n) {
    __shared__ int s[256];
    int i = blockIdx.x * 256 + threadIdx.x;
    int v = (i < n) ? cnt[i] : 0;
    s[threadIdx.x] = v;
    __syncthreads();
    for (int off = 1; off < 256; off <<= 1) {
        int t = (threadIdx.x >= off) ? s[threadIdx.x - off] : 0;
        __syncthreads();
        s[threadIdx.x] += t;
        __syncthreads();
    }
    if (i < n) excl[i] = s[threadIdx.x] - v;
    if (threadIdx.x == 255) bsum[blockIdx.x] = s[255];
}

// single-block scan; also zeroes Psum + the two fp8 dummy rows (folded memsets)
__global__ void k_scan2(int* __restrict__ bsum, int nb, float* __restrict__ Psum,
                        unsigned* __restrict__ dumA, unsigned* __restrict__ dumB) {
    if (threadIdx.x < 16) { dumA[threadIdx.x] = 0u; dumB[threadIdx.x] = 0u; }
    for (int i = threadIdx.x; i < 64 * 64; i += 1024) Psum[i] = 0.f;
    __shared__ int s[1024];
    int v = (threadIdx.x < nb) ? bsum[threadIdx.x] : 0;
    s[threadIdx.x] = v;
    __syncthreads();
    for (int off = 1; off < 1024; off <<= 1) {
        int t = (threadIdx.x >= off) ? s[threadIdx.x - off] : 0;
        __syncthreads();
        s[threadIdx.x] += t;
        __syncthreads();
    }
    if (threadIdx.x < nb) bsum[threadIdx.x] = s[threadIdx.x] - v;
}

// ---- partB: scatter compressed (src<<8|dloc) into bucket-grouped order --

__global__ __launch_bounds__(1024) void k_partB(const int* __restrict__ src,
                                                const int* __restrict__ dst,
                                                const int* __restrict__ Gh,
                                                const int* __restrict__ bsumG,
                                                unsigned* __restrict__ packed,
                                                int E, int nbuck, int chunk) {
    __shared__ int cur[512];
    for (int b = threadIdx.x; b < nbuck; b += blockDim.x)
        cur[b] = Gh[b * NBLK + blockIdx.x] + bsumG[b];
    __syncthreads();
    int base = blockIdx.x * chunk;
    int lim  = min(base + chunk, E);
    for (int e = base + threadIdx.x; e < lim; e += blockDim.x) {
        int d = dst[e], s = src[e];
        int pos = atomicAdd(&cur[d >> BSH], 1);
        packed[pos] = ((unsigned)s << 8) | (unsigned)(d & 255);
    }
}

// ---- placeC: per bucket — histogram -> PADDED rp2 + dinv + meta ---------

__global__ __launch_bounds__(512) void k_placeC(const unsigned* __restrict__ packed,
                                                const int* __restrict__ Gh,
                                                const int* __restrict__ bsumG,
                                                int2* __restrict__ rp2,
                                                float* __restrict__ dinv,
                                                int* __restrict__ meta,
                                                int nn, int nbuck, int E) {
    __shared__ int hist[256];
    __shared__ int scn[256];
    __shared__ int cur[256];
    int tid = threadIdx.x;
    int b   = blockIdx.x;
    int nb0 = b << BSH;
    int nnb = min(1 << BSH, nn - nb0);
    if (tid < 256) hist[tid] = 0;
    __syncthreads();
    int lo = Gh[b * NBLK] + bsumG[b];
    int hi = (b + 1 < nbuck) ? (Gh[(b + 1) * NBLK] + bsumG[b + 1]) : E;
    for (int e = lo + tid; e < hi; e += blockDim.x)
        atomicAdd(&hist[packed[e] & 255u], 1);
    __syncthreads();
    int pd = 0;
    if (tid < 256) { pd = (hist[tid] + 3) & ~3; scn[tid] = pd; }
    __syncthreads();
    for (int off = 1; off < 256; off <<= 1) {
        int t = 0;
        if (tid < 256 && tid >= off) t = scn[tid - off];
        __syncthreads();
        if (tid < 256) scn[tid] += t;
        __syncthreads();
    }
    int meta0 = ((lo + 3) & ~3) + BPAD * b;   // aligned bucket meta start
    if (tid < nnb) {
        int rp = meta0 + scn[tid] - pd;
        rp2[nb0 + tid] = make_int2(rp, rp + pd);
        cur[tid] = rp;
        dinv[nb0 + tid] = rsqrtf((float)(hist[tid] + 1));  // +1 self loop
        for (int k = hist[tid]; k < pd; k++) meta[rp + k] = nn;  // pads
    }
    __syncthreads();
    for (int e = lo + tid; e < hi; e += blockDim.x) {
        unsigned p = packed[e];
        int pos = atomicAdd(&cur[p & 255u], 1);
        meta[pos] = (int)(p >> 8);
    }
}

// ---- Dense X@W via MFMA bf16 + dinv-scaled fp8 epilogue -----------------

template <int K, bool IN_BF16>
__global__ __launch_bounds__(256) void k_gemm(const void* __restrict__ Xv,
                                              const float* __restrict__ W,
                                              const float* __restrict__ dinv,
                                              unsigned char* __restrict__ G8, int n) {
    constexpr int KS = K + 8;
    __shared__ bfu wt[64 * KS];
    int tid = threadIdx.x;
    for (int i = tid; i < K * 64; i += 256) {     // stage W^T as bf16 (RNE)
        int k = i >> 6, nn2 = i & 63;
        wt[nn2 * KS + k] = bf16_of(W[i]);
    }
    __syncthreads();
    int wave = tid >> 6, lane = tid & 63;
    int m = lane & 15, q = lane >> 4;
    int row0 = blockIdx.x * 64 + wave * 16;
    int rowA = min(row0 + m, n - 1);              // clamp: OOB rows never stored
    f32x4 acc[4] = {{0.f,0.f,0.f,0.f},{0.f,0.f,0.f,0.f},
                    {0.f,0.f,0.f,0.f},{0.f,0.f,0.f,0.f}};
#pragma unroll
    for (int ks = 0; ks < K / 32; ks++) {
        bf16x8 a;
        if (IN_BF16) {
            a = *(const bf16x8*)((const bfu*)Xv + (size_t)rowA * 64 + ks * 32 + q * 8);
        } else {
            const float* xp = (const float*)Xv + (size_t)rowA * K + ks * 32 + q * 8;
            float4 v0 = *(const float4*)xp;
            float4 v1 = *(const float4*)(xp + 4);
            union { unsigned u[4]; bf16x8 v; } cvt;
            cvt.u[0] = __builtin_amdgcn_perm(__float_as_uint(v0.y), __float_as_uint(v0.x), 0x07060302u);
            cvt.u[1] = __builtin_amdgcn_perm(__float_as_uint(v0.w), __float_as_uint(v0.z), 0x07060302u);
            cvt.u[2] = __builtin_amdgcn_perm(__float_as_uint(v1.y), __float_as_uint(v1.x), 0x07060302u);
            cvt.u[3] = __builtin_amdgcn_perm(__float_as_uint(v1.w), __float_as_uint(v1.z), 0x07060302u);
            a = cvt.v;
        }
#pragma unroll
        for (int nt = 0; nt < 4; nt++) {
            bf16x8 b = *(const bf16x8*)&wt[(nt * 16 + m) * KS + ks * 32 + q * 8];
            acc[nt] = __builtin_amdgcn_mfma_f32_16x16x32_bf16(a, b, acc[nt], 0, 0, 0);
        }
    }
#pragma unroll
    for (int r = 0; r < 4; r++) {
        int grow = row0 + q * 4 + r;
        if (grow < n) {
            float dv = dinv[grow];
            int p01 = fp8_pk<false>(acc[0][r] * dv, acc[1][r] * dv, 0);
            int p23 = fp8_pk<false>(acc[2][r] * dv, acc[3][r] * dv, 0);
            unsigned char* gp = G8 + (size_t)grow * 64 + m;
            gp[0]  = (unsigned char)(p01 & 0xFF);
            gp[16] = (unsigned char)((p01 >> 8) & 0xFF);
            gp[32] = (unsigned char)(p23 & 0xFF);
            gp[48] = (unsigned char)((p23 >> 8) & 0xFF);
        }
    }
}

// ---- CSR gather agg: EQUAD-PER-NODE (4 nodes/wave, 16 lanes x 4 cols) ---
// No cross-lane reduction: each equad walks its own node's padded edge
// list 4 edges at a time (int4 meta, equad-uniform) and keeps its 4 column
// accumulators in-lane. Divergence across equads bounded by max-degree/4.

template <bool OUT_FP8>
__global__ void k_agg(const unsigned* __restrict__ G4, const int* __restrict__ meta,
                      const int2* __restrict__ rp2, const float* __restrict__ dinv,
                      const float* __restrict__ bias, void* __restrict__ outv,
                      int n, int do_relu, int post_scale) {
    int wbase = ((blockIdx.x * blockDim.x + threadIdx.x) >> 6) * 4;
    if (wbase >= n) return;
    int lane = threadIdx.x & 63;
    int col4 = lane & 15, equad = lane >> 4;
    int nd    = wbase + equad;
    bool alive = nd < n;
    int ndc   = alive ? nd : (n - 1);
    int2 rp = rp2[ndc];
    int beg = rp.x, pend = alive ? rp.y : rp.x;
    f32x2 aA = {0.f, 0.f}, aB = {0.f, 0.f};
    for (int e = beg; e < pend; e += 4) {
        int4 m = *(const int4*)&meta[e];
        unsigned d0 = G4[(size_t)m.x * 16 + col4];
        unsigned d1 = G4[(size_t)m.y * 16 + col4];
        unsigned d2 = G4[(size_t)m.z * 16 + col4];
        unsigned d3 = G4[(size_t)m.w * 16 + col4];
        aA += fp8_unpk<false>(d0); aB += fp8_unpk<true>(d0);
        aA += fp8_unpk<false>(d1); aB += fp8_unpk<true>(d1);
        aA += fp8_unpk<false>(d2); aB += fp8_unpk<true>(d2);
        aA += fp8_unpk<false>(d3); aB += fp8_unpk<true>(d3);
    }
    unsigned sv = G4[(size_t)ndc * 16 + col4];   // self loop (pre-scaled)
    aA += fp8_unpk<false>(sv); aB += fp8_unpk<true>(sv);
    float dv = dinv[ndc];
    float a0 = aA.x * dv, a1 = aA.y * dv, a2 = aB.x * dv, a3 = aB.y * dv;
    if (bias) {
        float4 bv = *(const float4*)&bias[col4 * 4];
        a0 += bv.x; a1 += bv.y; a2 += bv.z; a3 += bv.w;
    }
    if (do_relu) {
        a0 = fmaxf(a0, 0.f); a1 = fmaxf(a1, 0.f);
        a2 = fmaxf(a2, 0.f); a3 = fmaxf(a3, 0.f);
    }
    if (post_scale) { a0 *= dv; a1 *= dv; a2 *= dv; a3 *= dv; }
    if (alive) {
        if (OUT_FP8) {
            int p = fp8_pk<false>(a0, a1, 0);
            p = fp8_pk<true>(a2, a3, p);
            ((unsigned*)outv)[(size_t)nd * 16 + col4] = (unsigned)p;
        } else {
            uint2 o;
            o.x = (unsigned)bf16_of(a0) | ((unsigned)bf16_of(a1) << 16);
            o.y = (unsigned)bf16_of(a2) | ((unsigned)bf16_of(a3) << 16);
            ((uint2*)outv)[(size_t)nd * 16 + col4] = o;
        }
    }
}

// ---- Mean pool, chunk-parallel (bf16 input, fp32 accum) -----------------

__global__ void k_pool(const bfu* __restrict__ G, const int* __restrict__ batch,
                       float* __restrict__ Psum, int n) {
    int base = blockIdx.x * 256;
    int lane = threadIdx.x & 63, rg = threadIdx.x >> 6;
    int lim = min(base + 256, n);
    int cur = -1;
    float acc = 0.f;
    for (int r = base + rg; r < lim; r += 4) {
        int g = batch[r];
        if (g != cur) {
            if (cur >= 0) atomicAdd(&Psum[cur * 64 + lane], acc);
            cur = g;
            acc = 0.f;
        }
        acc += f_of_bf16(G[(size_t)r * 64 + lane]);
    }
    if (cur >= 0) atomicAdd(&Psum[cur * 64 + lane], acc);
}

// ---- mean + pooled@W3 + b3 + log_softmax --------------------------------

__global__ void k_final(const float* __restrict__ Psum, const int* __restrict__ batch,
                        int n, const float* __restrict__ W3, const float* __restrict__ b3,
                        float* __restrict__ out, int ng) {
    __shared__ float P[64 * 64];
    __shared__ float s[64][NC];
    __shared__ float lse[64];
    __shared__ float invc[64];
    int t = threadIdx.x;
    if (t < ng) {
        int lo = lower_bound_i(batch, n, t);
        int hi = lower_bound_i(batch, n, t + 1);
        invc[t] = 1.f / (float)max(hi - lo, 1);
    }
    __syncthreads();
    for (int i = t; i < ng * 64; i += blockDim.x) P[i] = Psum[i] * invc[i >> 6];
    __syncthreads();
    if (t < ng * NC) {
        int g = t / NC, c = t % NC;
        float acc = b3[c];
        for (int k = 0; k < 64; k++) acc += P[g * 64 + k] * W3[k * NC + c];
        s[g][c] = acc;
    }
    __syncthreads();
    if (t < ng) {
        float m = -1e30f;
        for (int c = 0; c < NC; c++) m = fmaxf(m, s[t][c]);
        float sum = 0.f;
        for (int c = 0; c < NC; c++) sum += expf(s[t][c] - m);
        lse[t] = m + logf(sum);
    }
    __syncthreads();
    if (t < ng * NC) {
        int g = t / NC, c = t % NC;
        out[t] = s[g][c] - lse[g];
    }
}

// ---- launch -------------------------------------------------------------

extern "C" void kernel_launch(void* const* d_in, const int* in_sizes, int n_in,
                              void* d_out, int out_size, void* d_ws, size_t ws_size,
                              hipStream_t stream) {
    const float* x     = (const float*)d_in[0];
    const int*   ei    = (const int*)  d_in[1];
    const int*   batch = (const int*)  d_in[2];
    const float* W1    = (const float*)d_in[3];
    const float* b1    = (const float*)d_in[4];
    const float* W2    = (const float*)d_in[5];
    const float* b2    = (const float*)d_in[6];
    const float* W3    = (const float*)d_in[7];
    const float* b3    = (const float*)d_in[8];
    float*       out   = (float*)d_out;

    const int NN = in_sizes[0] / IN_CH;   // 100000
    const int E  = in_sizes[1] / 2;       // 1600000
    const int NG = out_size / NC;         // 64
    const int nbuck = (NN + (1 << BSH) - 1) >> BSH;  // 391

    const int* src = ei;
    const int* dst = ei + E;

    char* ws = (char*)d_ws;
    size_t off = 0;
    auto carve = [&](size_t bytes) -> char* {
        char* p = ws + off;
        off = (off + bytes + 255) & ~(size_t)255;
        return p;
    };
    int2*  rp2    = (int2*) carve((size_t)NN * 8);
    float* dinv   = (float*)carve((size_t)NN * 4);
    int*   bsumG  = (int*)  carve(4096);
    int*   Gh     = (int*)  carve((size_t)nbuck * NBLK * 4);
    int*   meta   = (int*)  carve(((size_t)E + (size_t)BPAD * nbuck + 64) * 4);
    unsigned char* f8A = (unsigned char*)carve((size_t)(NN + 1) * 64);  // G1 then G3
    unsigned char* f8B = (unsigned char*)carve((size_t)(NN + 1) * 64);  // G2
    bfu*   hbuf   = (bfu*)  carve((size_t)NN * HID * 2);  // H1, then agg3 out
    float* Psum   = (float*)carve((size_t)NG * HID * 4);
    (void)ws_size;

    unsigned* packed = (unsigned*)hbuf;   // E*4 = 6.4 MB fits (dead until agg1)

    const int nbN  = (NN + 255) / 256;          // 391
    const int nG   = nbuck * NBLK;              // 100096
    const int nbGh = (nG + 255) / 256;          // 391
    const int chnk = (E + NBLK - 1) / NBLK;     // 6250

    k_hist<<<NBLK, 1024, 0, stream>>>(dst, Gh, E, nbuck, chnk);
    k_scan1<<<nbGh, 256, 0, stream>>>(Gh, Gh, bsumG, nG);
    k_scan2<<<1, 1024, 0, stream>>>(bsumG, nbGh, Psum,
                                    (unsigned*)(f8A + (size_t)NN * 64),
                                    (unsigned*)(f8B + (size_t)NN * 64));
    k_partB <<<NBLK, 1024, 0, stream>>>(src, dst, Gh, bsumG, packed, E, nbuck, chnk);
    k_placeC<<<nbuck, 512, 0, stream>>>(packed, Gh, bsumG, rp2, dinv,
                                        meta, NN, nbuck, E);

    const int nbG = (NN + 63) / 64;             // 1563 (64 rows per block)
    const int nbA = (NN + 15) / 16;             // 6250 (16 nodes per block)

    // layer 1: G1 = fp8(dinv*(x@W1)) ; H1 = bf16(relu(dinv*(G1[v]+sum)+b1))
    k_gemm<IN_CH, false><<<nbG, 256, 0, stream>>>(x, W1, dinv, f8A, NN);
    k_agg<false><<<nbA, 256, 0, stream>>>((const unsigned*)f8A, meta, rp2,
                                          dinv, b1, hbuf, NN, 1, 0);
    // layer 2: G2 = fp8(dinv*(H1@W2)) ; G3 = fp8(dinv*relu(dinv*(...)+b2))
    k_gemm<HID, true><<<nbG, 256, 0, stream>>>(hbuf, W2, dinv, f8B, NN);
    k_agg<true><<<nbA, 256, 0, stream>>>((const unsigned*)f8B, meta, rp2,
                                         dinv, b2, f8A, NN, 1, 1);
    // layer 3 (reordered): p = dinv*(G3[v]+sum G3[src]) -> bf16 ; pool ; head
    k_agg<false><<<nbA, 256, 0, stream>>>((const unsigned*)f8A, meta, rp2,
                                          dinv, nullptr, hbuf, NN, 0, 0);
    k_pool<<<nbN, 256, 0, stream>>>(hbuf, batch, Psum, NN);
    k_final<<<1, 640, 0, stream>>>(Psum, batch, NN, W3, b3, out, NG);
}